// Round 11
// baseline (247.274 us; speedup 1.0000x reference)
//
#include <hip/hip_runtime.h>
#include <math.h>

#define BB 32
#define CC 256
#define TT 1024

typedef __attribute__((ext_vector_type(4))) float f4;
typedef __attribute__((ext_vector_type(4))) float f32x4;
typedef __attribute__((ext_vector_type(16))) float f32x16;
typedef __attribute__((ext_vector_type(8))) short s8;   // bf16x8 MFMA frag (4 VGPRs)
typedef __attribute__((ext_vector_type(4))) short s4v;  // 8B LDS store
typedef __attribute__((ext_vector_type(4))) int i32x4;

__device__ inline short f2bf(float f) {                 // RNE fp32->bf16
    unsigned u = __builtin_bit_cast(unsigned, f);
    u = (u + 0x7FFFu + ((u >> 16) & 1u)) >> 16;
    return (short)u;
}

// fragment-order offset for a (64-row Q/K tile, row, d-octet) — layout:
//   Q/K: [b][t64][half(row>>5)][kc(d>>4)][lh((d>>3)&1)][l31(row&31)][8]
__device__ inline size_t fo_qk(int b, int t64, int row, int sg) {
    int th = row >> 5, tl = row & 31, kc = sg >> 4, lhh = (sg >> 3) & 1;
    return ((((((size_t)b * 16 + t64) * 2 + th) * 4 + kc) * 2 + lhh) * 32 + tl) * 8;
}

// ---- workspace layout (bytes) ----
// qbf/kbf/vt in MFMA-FRAGMENT ORDER (R18 layout, correctness-proven):
//   Q/K: [b][t64][th][kc][lh][l31][8]  V: [b][kt64][ctile][kc][lh][l31][8]
static const size_t OFF_QBF  = 0;          // 4 MB
static const size_t OFF_KBF  = 4194304;    // 4 MB
static const size_t OFF_VT   = 8388608;    // 16 MB
static const size_t OFF_OA   = 25165824;   // [B][T][C]: xt bf16 -> oa bf16 (16 MB used of 32)
static const size_t OFF_C1   = 58720256;   // [B][T][C]  bf16  16 MB (conv1 out)
static const size_t OFF_CRZ  = 75497472;   // [B][T] fp32 col 1/Z
static const size_t OFF_RS   = 75628544;   // [B][T] fp32 rowsum
static const size_t OFF_WX   = 75759616;   // [B][T] fp32 weight_x
static const size_t OFF_W1   = 75890688;   // [3][256][256] bf16 W1 [j][o][c]
static const size_t OFF_W2   = 76283904;   // [3][256][256] bf16 W2
static const size_t OFF_WQKV = 76677120;   // [384][256] bf16 (q|k|v) [n][c]

// ---------------------------------------------------------------------------
__global__ __launch_bounds__(256)
void wn_kernel(const float* __restrict__ v1, const float* __restrict__ g1,
               const float* __restrict__ v2, const float* __restrict__ g2,
               short* __restrict__ w1bf, short* __restrict__ w2bf) {
    __shared__ float red[4];
    int which = blockIdx.x >> 8, o = blockIdx.x & 255;
    const float* v = which ? v2 : v1;
    const float* g = which ? g2 : g1;
    short* wt = which ? w2bf : w1bf;
    const float* row = v + (size_t)o * 768;
    int tid = threadIdx.x, lane = tid & 63, wv_ = tid >> 6;
    float r0 = row[tid], r1 = row[tid + 256], r2 = row[tid + 512];
    float s = r0 * r0 + r1 * r1 + r2 * r2;
    for (int d = 1; d < 64; d <<= 1) s += __shfl_xor(s, d, 64);
    if (lane == 0) red[wv_] = s;
    __syncthreads();
    float scale = g[o] * rsqrtf(red[0] + red[1] + red[2] + red[3]);
    for (int j = 0; j < 3; ++j)
        wt[((size_t)(j * 256 + o)) * 256 + tid] = f2bf(scale * row[tid * 3 + j]);
}

__global__ __launch_bounds__(256)
void pack_kernel(const float* __restrict__ wq, const float* __restrict__ wk,
                 const float* __restrict__ wv, short* __restrict__ wqkvbf) {
    int n = blockIdx.x * 4 + (threadIdx.x >> 6);
    int c0 = (threadIdx.x & 63) * 4;
    for (int p = 0; p < 4; ++p) {
        int c = c0 + p;
        float w;
        if (n < 64)       w = wq[c * 64 + n];
        else if (n < 128) w = wk[c * 64 + n - 64];
        else              w = wv[c * 256 + n - 128];
        wqkvbf[(size_t)n * 256 + c] = f2bf(w);
    }
}

// ---------------------------------------------------------------------------
__global__ void transpose_kernel(const float* __restrict__ x, short* __restrict__ xt) {
    __shared__ float Tt[64 * 68];
    int tid = threadIdx.x;
    int c0 = blockIdx.x * 64, t0 = blockIdx.y * 64, b = blockIdx.z;
    for (int it = 0; it < 4; ++it) {
        int idx = tid + 256 * it;
        int cr = idx >> 4, tc = idx & 15;
        f4 v = *reinterpret_cast<const f4*>(&x[((size_t)b * CC + c0 + cr) * TT + t0 + tc * 4]);
        *reinterpret_cast<f4*>(&Tt[cr * 68 + tc * 4]) = v;
    }
    __syncthreads();
    for (int it = 0; it < 2; ++it) {
        int idx = tid + 256 * it;
        int tl = idx >> 3, seg = idx & 7;
        s8 o;
        for (int p = 0; p < 8; ++p) o[p] = f2bf(Tt[(seg * 8 + p) * 68 + tl]);
        *reinterpret_cast<s8*>(&xt[((size_t)b * TT + t0 + tl) * CC + c0 + seg * 8]) = o;
    }
}

// ---------------------------------------------------------------------------
// qkv: R18's fragment-order producer (correctness-proven). 1D grid 1536.
__global__ __launch_bounds__(256, 3)
void qkv_kernel(const short* __restrict__ xt, const short* __restrict__ wqkv,
                const float* __restrict__ bq, const float* __restrict__ bk,
                const float* __restrict__ bv,
                short* __restrict__ qbf, short* __restrict__ kbf, short* __restrict__ vt) {
    __shared__ short SL[128 * 72 + 64 * 72];   // A (128t x 64c) then B (64n x 64c)
    short* Asm = SL;
    short* Bsm = SL + 128 * 72;
    int tid = threadIdx.x, wv_ = tid >> 6, lane = tid & 63;
    int n15 = lane & 15, quad = lane >> 4;
    int bid = blockIdx.x;
    int r = bid & 7, n = (bid >> 3) % 6, qd = bid / 48;
    int bt = qd * 8 + r;
    int b = bt >> 3, t0 = (bt & 7) * 128;
    int n0 = n * 64;

    f32x4 acc[2][4];
    for (int i = 0; i < 2; ++i) for (int j = 0; j < 4; ++j)
        for (int p = 0; p < 4; ++p) acc[i][j][p] = 0.f;

    for (int kc = 0; kc < 4; ++kc) {
        int c0 = kc * 64;
        __syncthreads();
        for (int it = 0; it < 4; ++it) {
            int idx = tid + 256 * it;
            int row = idx >> 3, seg = idx & 7;
            *reinterpret_cast<s8*>(&Asm[row * 72 + seg * 8]) =
                *reinterpret_cast<const s8*>(&xt[((size_t)b * TT + t0 + row) * CC + c0 + seg * 8]);
        }
        for (int it = 0; it < 2; ++it) {
            int idx = tid + 256 * it;
            int row = idx >> 3, seg = idx & 7;
            *reinterpret_cast<s8*>(&Bsm[row * 72 + seg * 8]) =
                *reinterpret_cast<const s8*>(&wqkv[(size_t)(n0 + row) * 256 + c0 + seg * 8]);
        }
        __syncthreads();
        for (int ks = 0; ks < 2; ++ks)
            for (int mt2 = 0; mt2 < 2; ++mt2) {
                s8 a = *reinterpret_cast<const s8*>(&Asm[(wv_ * 32 + mt2 * 16 + n15) * 72 + quad * 8 + ks * 32]);
                for (int nt = 0; nt < 4; ++nt) {
                    s8 bb = *reinterpret_cast<const s8*>(&Bsm[(nt * 16 + n15) * 72 + quad * 8 + ks * 32]);
                    acc[mt2][nt] = __builtin_amdgcn_mfma_f32_16x16x32_bf16(a, bb, acc[mt2][nt], 0, 0, 0);
                }
            }
    }
    if (n0 < 128) {
        short* outp = (n0 == 0) ? qbf : kbf;
        const float* bias = (n0 == 0) ? bq : bk;
        for (int mt2 = 0; mt2 < 2; ++mt2)
            for (int nt = 0; nt < 4; ++nt) {
                int n_ = nt * 16 + n15;               // d index 0..63
                int kc = n_ >> 4, lhh = (n_ >> 3) & 1, j = n_ & 7;
                float bvl = bias[n_];
                for (int reg = 0; reg < 4; ++reg) {
                    int t = t0 + wv_ * 32 + mt2 * 16 + quad * 4 + reg;
                    int tt = t >> 6, th = (t >> 5) & 1, tl = t & 31;
                    size_t idx = ((((((size_t)b * 16 + tt) * 2 + th) * 4 + kc) * 2 + lhh) * 32 + tl) * 8 + j;
                    outp[idx] = f2bf(acc[mt2][nt][reg] + bvl);
                }
            }
    } else {
        int cbase = n0 - 128;
        __syncthreads();
        short* Tw = SL + wv_ * 3072;
        for (int mt2 = 0; mt2 < 2; ++mt2)
            for (int nt = 0; nt < 4; ++nt) {
                int n_ = nt * 16 + n15;
                float bvl = bv[cbase + n_];
                for (int reg = 0; reg < 4; ++reg)
                    Tw[n_ * 48 + mt2 * 16 + quad * 4 + reg] = f2bf(acc[mt2][nt][reg] + bvl);
            }
        for (int p = 0; p < 4; ++p) {
            int n_ = (lane >> 2) + 16 * p;
            int seg = lane & 3;
            s8 vv = *reinterpret_cast<const s8*>(&Tw[n_ * 48 + seg * 8]);
            int c = cbase + n_;
            int t = t0 + wv_ * 32 + seg * 8;          // 8-aligned t octet
            int kt = t >> 6, tl = t & 63;
            int kc = tl >> 4, lhh = (tl >> 3) & 1;
            size_t idx = ((((((size_t)b * 16 + kt) * 8 + (c >> 5)) * 4 + kc) * 2 + lhh) * 32 + (c & 31)) * 8;
            *reinterpret_cast<s8*>(&vt[idx]) = vv;
        }
    }
}

// ---------------------------------------------------------------------------
// colz: R17 structure verbatim (the proven -30µs config); ONLY the global
// source addresses are remapped to fragment order via fo_qk (LDS layout and
// MFMA frag reads unchanged). XCD decode b = bid&31.
__global__ __launch_bounds__(512, 2)
void colz_kernel(const short* __restrict__ qbf, const short* __restrict__ kbf,
                 float* __restrict__ colrz) {
    __shared__ short Qs[4][64 * 72];
    __shared__ short Ks[64 * 72];
    __shared__ float redz[8][2][32];
    int tid = threadIdx.x, wv_ = tid >> 6, lane = tid & 63;
    int l31 = lane & 31, lh = lane >> 5;
    int qh = wv_ & 1, ti = wv_ >> 1;     // q-half, qt-tile within unit
    int b = blockIdx.x & 31, pr = blockIdx.x >> 5;
    int kts[2] = {pr, 15 - pr};
    int row = tid >> 3, sg = (tid & 7) * 8;

    s8 kr = *reinterpret_cast<const s8*>(&kbf[fo_qk(b, kts[0], row, sg)]);
    s8 qreg[4];
    for (int j = 0; j < 4; ++j) {
        int t = kts[0] + j; if (t > 15) t = 15;
        qreg[j] = *reinterpret_cast<const s8*>(&qbf[fo_qk(b, t, row, sg)]);
    }

    for (int ph = 0; ph < 2; ++ph) {
        int kt = kts[ph];
        float zl[2] = {0.f, 0.f};
        for (int u = kt; u < 16; u += 4) {
            __syncthreads();                       // B-top: Qs reuse safe
            if (u == kt) *reinterpret_cast<s8*>(&Ks[row * 72 + sg]) = kr;
            for (int j = 0; j < 4; ++j)
                *reinterpret_cast<s8*>(&Qs[j][row * 72 + sg]) = qreg[j];
            __syncthreads();                       // B-stage
            int nu = u + 4;
            if (nu < 16) {
                for (int j = 0; j < 4; ++j) {
                    int t = nu + j; if (t > 15) t = 15;
                    qreg[j] = *reinterpret_cast<const s8*>(&qbf[fo_qk(b, t, row, sg)]);
                }
            } else if (ph == 0) {
                int k2 = kts[1];
                kr = *reinterpret_cast<const s8*>(&kbf[fo_qk(b, k2, row, sg)]);
                for (int j = 0; j < 4; ++j) {
                    int t = k2 + j; if (t > 15) t = 15;
                    qreg[j] = *reinterpret_cast<const s8*>(&qbf[fo_qk(b, t, row, sg)]);
                }
            }
            int qtw = u + ti;
            if (qtw < 16) {
                for (int kh = 0; kh < 2; ++kh) {
                    f32x16 s;
                    for (int p = 0; p < 16; ++p) s[p] = 0.f;
                    for (int kc = 0; kc < 4; ++kc) {
                        s8 a  = *reinterpret_cast<const s8*>(&Qs[ti][(qh * 32 + l31) * 72 + kc * 16 + lh * 8]);
                        s8 bb = *reinterpret_cast<const s8*>(&Ks[(kh * 32 + l31) * 72 + kc * 16 + lh * 8]);
                        s = __builtin_amdgcn_mfma_f32_32x32x16_bf16(a, bb, s, 0, 0, 0);
                    }
                    int kg = kt * 64 + kh * 32 + l31;
                    int qb0 = qtw * 64 + qh * 32 + 4 * lh;
                    if (qtw > kt) {
                        for (int reg = 0; reg < 16; ++reg)
                            zl[kh] += __expf(s[reg] * 0.125f);
                    } else {
                        for (int reg = 0; reg < 16; ++reg) {
                            int rr = (reg & 3) + 8 * (reg >> 2);
                            if (qb0 + rr >= kg) zl[kh] += __expf(s[reg] * 0.125f);
                        }
                    }
                }
            }
        }
        for (int kh = 0; kh < 2; ++kh) {
            float zc = zl[kh] + __shfl_xor(zl[kh], 32, 64);
            if (lane < 32) redz[wv_][kh][lane] = zc;
        }
        __syncthreads();
        if (tid < 64) {
            int kh = tid >> 5, kk = tid & 31;
            float Z = 0.f;
            for (int w = 0; w < 8; ++w) Z += redz[w][kh][kk];
            colrz[(size_t)b * TT + kt * 64 + tid] = 1.0f / Z;
        }
        __syncthreads();
    }
}

// ---------------------------------------------------------------------------
// attn: R21 — barrier-free in-register-P waves (guide §B mechanism).
// Swapped QK^T: S^T = mfma(A=K, B=Q) -> lane l31 holds q-row l31's k-values
// in regs (k_local = (r&3)+8*(r>>2)+4*lh). PV B-frag (P[q=l31][k]) assembled
// in-register: 8 bf16-packs + 8 shfl_xor(32) (lh-halves exchange), verified:
// frag[h] = lh==0 ? {w[4h],w[4h+1],x[4h],x[4h+1]}
//                 : {x[4h+2],x[4h+3],w[4h+2],w[4h+3]}.
// Wave = (32q tile-pair {31-pr, pr}) x (c-half ch) x (kt-parity par): fully
// independent main loop, Q/K/V frags direct from fragment-order global
// (R18-proven loads, FETCH at ideal), ZERO barriers until the epilogue,
// where parity partials merge + transpose through LDS (stride-261 conflict-
// free) for coalesced row-major O. rowsum is lane-local + 1 shfl.
// Block 4 waves x 256 thr, grid 512, LDS 67KB -> 2 blocks/CU. XCD b=bid&31.
__global__ __launch_bounds__(256, 2)
void attn_kernel(const short* __restrict__ qbf, const short* __restrict__ kbf,
                 const short* __restrict__ vt, const float* __restrict__ colrz,
                 short* __restrict__ oab, float* __restrict__ rowsum) {
    __shared__ float Om[2][32 * 261];   // [par][q][c] fp32 merge (66.8KB)
    __shared__ float redS[2][32];
    int tid = threadIdx.x, wv_ = tid >> 6, lane = tid & 63;
    int l31 = lane & 31, lh = lane >> 5;
    int par = wv_ & 1, ch = wv_ >> 1;
    int b = blockIdx.x & 31, pr = blockIdx.x >> 5;
    int tiles[2] = {31 - pr, pr};

    for (int ph = 0; ph < 2; ++ph) {
        int qi = tiles[ph];
        int qt64 = qi >> 1, qh = qi & 1;
        s8 qf[4];
        #pragma unroll
        for (int kc = 0; kc < 4; ++kc)
            qf[kc] = *reinterpret_cast<const s8*>(
                &qbf[((((((size_t)b * 16 + qt64) * 2 + qh) * 4 + kc) * 2 + lh) * 32 + l31) * 8]);
        f32x16 acc[4];
        #pragma unroll
        for (int i = 0; i < 4; ++i)
            for (int p = 0; p < 16; ++p) acc[i][p] = 0.f;
        float rsum = 0.f;
        int qg = qi * 32 + l31;

        for (int kt = par; kt <= qi; kt += 2) {
            int kt64 = kt >> 1, kh = kt & 1;
            // K frags (1KB/wave each, contiguous)
            s8 kf[4];
            #pragma unroll
            for (int kc = 0; kc < 4; ++kc)
                kf[kc] = *reinterpret_cast<const s8*>(
                    &kbf[((((((size_t)b * 16 + kt64) * 2 + kh) * 4 + kc) * 2 + lh) * 32 + l31) * 8]);
            // V frags for this wave's c-half (issued early; consumed after pack)
            s8 vf[8];
            #pragma unroll
            for (int ctl = 0; ctl < 4; ++ctl)
                for (int h = 0; h < 2; ++h) {
                    int kc = kh * 2 + h;
                    vf[ctl * 2 + h] = *reinterpret_cast<const s8*>(
                        &vt[((((((size_t)b * 16 + kt64) * 8 + (ch * 4 + ctl)) * 4 + kc) * 2 + lh) * 32 + l31) * 8]);
                }
            // S^T = K·Q^T over d=64
            f32x16 s;
            #pragma unroll
            for (int p = 0; p < 16; ++p) s[p] = 0.f;
            #pragma unroll
            for (int kc = 0; kc < 4; ++kc)
                s = __builtin_amdgcn_mfma_f32_32x32x16_bf16(kf[kc], qf[kc], s, 0, 0, 0);
            // mask + exp + rz; P stays in-register
            float p[16];
            int kb0 = kt * 32;
            #pragma unroll
            for (int r = 0; r < 16; ++r) {
                int kg = kb0 + (r & 3) + 8 * (r >> 2) + 4 * lh;
                float rz = colrz[(size_t)b * TT + kg];
                float pv = 0.f;
                if (kg <= qg) pv = __expf(s[r] * 0.125f) * rz;
                p[r] = pv;
                rsum += pv;
            }
            // pack to bf16 words + lh-exchange
            unsigned w[8], x[8];
            #pragma unroll
            for (int r2 = 0; r2 < 8; ++r2) {
                unsigned lo = (unsigned short)f2bf(p[2 * r2]);
                unsigned hi = (unsigned short)f2bf(p[2 * r2 + 1]);
                w[r2] = lo | (hi << 16);
            }
            #pragma unroll
            for (int i = 0; i < 8; ++i)
                x[i] = (unsigned)__shfl_xor((int)w[i], 32, 64);
            // PV: O^T[c][q] += V[c][k]·P[q][k], two k-chunks
            #pragma unroll
            for (int h = 0; h < 2; ++h) {
                i32x4 fi;
                if (lh == 0) {
                    fi[0] = (int)w[4 * h];     fi[1] = (int)w[4 * h + 1];
                    fi[2] = (int)x[4 * h];     fi[3] = (int)x[4 * h + 1];
                } else {
                    fi[0] = (int)x[4 * h + 2]; fi[1] = (int)x[4 * h + 3];
                    fi[2] = (int)w[4 * h + 2]; fi[3] = (int)w[4 * h + 3];
                }
                s8 pb = __builtin_bit_cast(s8, fi);
                #pragma unroll
                for (int ctl = 0; ctl < 4; ++ctl)
                    acc[ctl] = __builtin_amdgcn_mfma_f32_32x32x16_bf16(vf[ctl * 2 + h], pb, acc[ctl], 0, 0, 0);
            }
        }
        // ---- epilogue: merge parity partials, transpose, coalesced write ----
        __syncthreads();            // previous ph's Om reads complete
        #pragma unroll
        for (int ctl = 0; ctl < 4; ++ctl)
            for (int r = 0; r < 16; ++r) {
                int c = ch * 128 + ctl * 32 + (r & 3) + 8 * (r >> 2) + 4 * lh;
                Om[par][l31 * 261 + c] = acc[ctl][r];
            }
        float rtot = rsum + __shfl_xor(rsum, 32, 64);
        if (ch == 0 && lane < 32) redS[par][lane] = rtot;
        __syncthreads();
        for (int u = tid; u < 1024; u += 256) {
            int row = u >> 5, seg = u & 31;
            s8 o;
            #pragma unroll
            for (int j = 0; j < 8; ++j) {
                float v = Om[0][row * 261 + seg * 8 + j] + Om[1][row * 261 + seg * 8 + j];
                o[j] = f2bf(v);
            }
            *reinterpret_cast<s8*>(&oab[((size_t)b * TT + qi * 32 + row) * CC + seg * 8]) = o;
        }
        if (tid < 32)
            rowsum[(size_t)b * TT + qi * 32 + tid] = redS[0][tid] + redS[1][tid];
    }
}

// ---------------------------------------------------------------------------
// conv: 1D grid 1024, bid = q*32 + n0*8 + r (same-A blocks same XCD).
// R10: optional fused final epilogue (conv2): out[b,c,t] = relu(c2 + x*(1+wx))
// via LDS transpose — c2 (32 MB fp32) never touches HBM; final_kernel gone.
__global__ __launch_bounds__(256, 3)
void conv_kernel(const void* __restrict__ inp, int in_is_fp32,
                 const short* __restrict__ wbf, const float* __restrict__ bias,
                 void* __restrict__ outp, int out_is_bf16,
                 const float* __restrict__ xres, const float* __restrict__ wxv,
                 int fuse_final) {
    __shared__ short SL[130 * 72 + 3 * 64 * 72];   // As | Bs ; reused as Ft[128][67] fp32
    short* As = SL;
    short* Bs = SL + 130 * 72;
    int tid = threadIdx.x, wv_ = tid >> 6, lane = tid & 63;
    int n15 = lane & 15, quad = lane >> 4;
    int bid = blockIdx.x;
    int r = bid & 7;
    int n0 = ((bid >> 3) & 3) << 6;
    int bm = (bid >> 5) * 8 + r;
    int b = bm >> 3, mt = bm & 7;
    int t0 = mt * 128;
    f32x4 acc[2][4];
    for (int i = 0; i < 2; ++i) for (int j = 0; j < 4; ++j)
        for (int p = 0; p < 4; ++p) acc[i][j][p] = 0.f;

    for (int kc = 0; kc < 4; ++kc) {
        int c0 = kc * 64;
        __syncthreads();
        if (in_is_fp32) {
            const float* in = (const float*)inp;
            for (int it = 0; it < 9; ++it) {
                int idx = tid + 256 * it;
                int row = idx >> 4, fc = idx & 15;
                if (row < 130) {
                    int t = t0 + row - 2;
                    s4v st;
                    if (t >= 0) {
                        f4 v = *reinterpret_cast<const f4*>(&in[((size_t)b * TT + t) * CC + c0 + fc * 4]);
                        for (int p = 0; p < 4; ++p) st[p] = f2bf(v[p]);
                    } else { for (int p = 0; p < 4; ++p) st[p] = 0; }
                    *reinterpret_cast<s4v*>(&As[row * 72 + fc * 4]) = st;
                }
            }
        } else {
            const short* in = (const short*)inp;
            for (int it = 0; it < 5; ++it) {
                int idx = tid + 256 * it;
                int row = idx >> 3, seg = idx & 7;
                if (row < 130) {
                    int t = t0 + row - 2;
                    s8 st;
                    if (t >= 0) st = *reinterpret_cast<const s8*>(&in[((size_t)b * TT + t) * CC + c0 + seg * 8]);
                    else for (int p = 0; p < 8; ++p) st[p] = 0;
                    *reinterpret_cast<s8*>(&As[row * 72 + seg * 8]) = st;
                }
            }
        }
        for (int it = 0; it < 6; ++it) {
            int idx = tid + 256 * it;
            int row = idx >> 3, seg = idx & 7;
            int j = row >> 6, o = row & 63;
            *reinterpret_cast<s8*>(&Bs[row * 72 + seg * 8]) =
                *reinterpret_cast<const s8*>(&wbf[((size_t)(j * 256 + n0 + o)) * 256 + c0 + seg * 8]);
        }
        __syncthreads();
        for (int j = 0; j < 3; ++j)
            for (int ks = 0; ks < 2; ++ks)
                for (int mt2 = 0; mt2 < 2; ++mt2) {
                    s8 a = *reinterpret_cast<const s8*>(&As[(wv_ * 32 + mt2 * 16 + n15 + j) * 72 + quad * 8 + ks * 32]);
                    for (int nt = 0; nt < 4; ++nt) {
                        s8 bb = *reinterpret_cast<const s8*>(&Bs[(j * 64 + nt * 16 + n15) * 72 + quad * 8 + ks * 32]);
                        acc[mt2][nt] = __builtin_amdgcn_mfma_f32_16x16x32_bf16(a, bb, acc[mt2][nt], 0, 0, 0);
                    }
                }
    }
    if (!fuse_final) {
        for (int mt2 = 0; mt2 < 2; ++mt2)
            for (int nt = 0; nt < 4; ++nt) {
                int o = n0 + nt * 16 + n15;
                float bvl = bias[o];
                for (int reg = 0; reg < 4; ++reg) {
                    int t = t0 + wv_ * 32 + mt2 * 16 + quad * 4 + reg;
                    float v = fmaxf(acc[mt2][nt][reg] + bvl, 0.f);
                    if (out_is_bf16) ((short*)outp)[((size_t)b * TT + t) * CC + o] = f2bf(v);
                    else             ((float*)outp)[((size_t)b * TT + t) * CC + o] = v;
                }
            }
    } else {
        float* Ft = (float*)SL;            // [128][67] fp32 (34304 B <= SL)
        __syncthreads();                   // all LDS reads of As/Bs done
        for (int mt2 = 0; mt2 < 2; ++mt2)
            for (int nt = 0; nt < 4; ++nt) {
                int ol = nt * 16 + n15;
                float bvl = bias[n0 + ol];
                for (int reg = 0; reg < 4; ++reg) {
                    int tl = wv_ * 32 + mt2 * 16 + quad * 4 + reg;
                    Ft[tl * 67 + ol] = fmaxf(acc[mt2][nt][reg] + bvl, 0.f);
                }
            }
        __syncthreads();
        int c_l = tid >> 5;                // 0..7
        int t_l = (tid & 31) * 4;          // 0..124
        f4 wv4 = *reinterpret_cast<const f4*>(&wxv[(size_t)b * TT + t0 + t_l]);
        for (int pass = 0; pass < 8; ++pass) {
            int c = n0 + pass * 8 + c_l;
            f4 xv = *reinterpret_cast<const f4*>(&xres[((size_t)b * CC + c) * TT + t0 + t_l]);
            f4 rr;
            for (int p = 0; p < 4; ++p)
                rr[p] = fmaxf(Ft[(t_l + p) * 67 + pass * 8 + c_l] + xv[p] * (1.f + wv4[p]), 0.f);
            *reinterpret_cast<f4*>(&((float*)outp)[((size_t)b * CC + c) * TT + t0 + t_l]) = rr;
        }
    }
}

// ---------------------------------------------------------------------------
__global__ void rowsm_kernel(const float* __restrict__ rowsum, float* __restrict__ wx) {
    __shared__ float red[256];
    int b = blockIdx.x, tid = threadIdx.x;
    float v[4];
    float m = -1e30f;
    for (int r = 0; r < 4; ++r) { v[r] = rowsum[(size_t)b * TT + tid + 256 * r]; m = fmaxf(m, v[r]); }
    red[tid] = m; __syncthreads();
    for (int s = 128; s > 0; s >>= 1) { if (tid < s) red[tid] = fmaxf(red[tid], red[tid + s]); __syncthreads(); }
    m = red[0]; __syncthreads();
    float e[4], zs = 0.f;
    for (int r = 0; r < 4; ++r) { e[r] = __expf(v[r] - m); zs += e[r]; }
    red[tid] = zs; __syncthreads();
    for (int s = 128; s > 0; s >>= 1) { if (tid < s) red[tid] += red[tid + s]; __syncthreads(); }
    float rz = 1.0f / red[0];
    for (int r = 0; r < 4; ++r) wx[(size_t)b * TT + tid + 256 * r] = e[r] * rz;
}

// ---------------------------------------------------------------------------
extern "C" void kernel_launch(void* const* d_in, const int* in_sizes, int n_in,
                              void* d_out, int out_size, void* d_ws, size_t ws_size,
                              hipStream_t stream) {
    (void)in_sizes; (void)n_in; (void)out_size; (void)ws_size;
    const float* x  = (const float*)d_in[0];
    const float* wq = (const float*)d_in[1];
    const float* bq = (const float*)d_in[2];
    const float* wk = (const float*)d_in[3];
    const float* bk = (const float*)d_in[4];
    const float* wv = (const float*)d_in[5];
    const float* bv = (const float*)d_in[6];
    const float* v1 = (const float*)d_in[7];
    const float* g1 = (const float*)d_in[8];
    const float* b1 = (const float*)d_in[9];
    const float* v2 = (const float*)d_in[10];
    const float* g2 = (const float*)d_in[11];
    const float* b2 = (const float*)d_in[12];
    char* ws = (char*)d_ws;
    float* out = (float*)d_out;

    short* qbf  = (short*)(ws + OFF_QBF);
    short* kbf  = (short*)(ws + OFF_KBF);
    short* vt   = (short*)(ws + OFF_VT);
    short* xt   = (short*)(ws + OFF_OA);   // xt bf16 (dead after qkv)
    short* oab  = (short*)(ws + OFF_OA);   // oa bf16 (attn out; dead after conv1)
    short* c1   = (short*)(ws + OFF_C1);
    float* crz  = (float*)(ws + OFF_CRZ);
    float* rs   = (float*)(ws + OFF_RS);
    float* wxb  = (float*)(ws + OFF_WX);
    short* w1bf = (short*)(ws + OFF_W1);
    short* w2bf = (short*)(ws + OFF_W2);
    short* wqkv = (short*)(ws + OFF_WQKV);

    wn_kernel<<<dim3(512), dim3(256), 0, stream>>>(v1, g1, v2, g2, w1bf, w2bf);
    pack_kernel<<<dim3(96), dim3(256), 0, stream>>>(wq, wk, wv, wqkv);
    transpose_kernel<<<dim3(4, 16, 32), dim3(256), 0, stream>>>(x, xt);
    qkv_kernel<<<dim3(1536), dim3(256), 0, stream>>>(xt, wqkv, bq, bk, bv, qbf, kbf, vt);
    colz_kernel<<<dim3(256), dim3(512), 0, stream>>>(qbf, kbf, crz);
    attn_kernel<<<dim3(512), dim3(256), 0, stream>>>(qbf, kbf, vt, crz, oab, rs);
    rowsm_kernel<<<dim3(32), dim3(256), 0, stream>>>(rs, wxb);
    conv_kernel<<<dim3(1024), dim3(256), 0, stream>>>(oab, 0, w1bf, b1, c1, 1,
                                                      nullptr, nullptr, 0);
    conv_kernel<<<dim3(1024), dim3(256), 0, stream>>>(c1, 0, w2bf, b2, out, 0,
                                                      x, wxb, 1);
}

// Round 12
// 220.132 us; speedup vs baseline: 1.1233x; 1.1233x over previous
//
#include <hip/hip_runtime.h>
#include <math.h>

#define BB 32
#define CC 256
#define TT 1024

typedef __attribute__((ext_vector_type(4))) float f4;
typedef __attribute__((ext_vector_type(4))) float f32x4;
typedef __attribute__((ext_vector_type(16))) float f32x16;
typedef __attribute__((ext_vector_type(8))) short s8;   // bf16x8 MFMA frag (4 VGPRs)
typedef __attribute__((ext_vector_type(4))) short s4v;  // 8B LDS store

__device__ inline short f2bf(float f) {                 // RNE fp32->bf16
    unsigned u = __builtin_bit_cast(unsigned, f);
    u = (u + 0x7FFFu + ((u >> 16) & 1u)) >> 16;
    return (short)u;
}

// ---- workspace layout (bytes) ----
static const size_t OFF_QBF  = 0;          // [B][T][64] bf16   4 MB
static const size_t OFF_KBF  = 4194304;    // [B][T][64] bf16   4 MB
static const size_t OFF_VT   = 8388608;    // [B][C][T]  bf16  16 MB (v transposed)
static const size_t OFF_OA   = 25165824;   // [B][T][C]: xt bf16 -> oa bf16 (16 MB used of 32)
static const size_t OFF_C1   = 58720256;   // [B][T][C]  bf16  16 MB (conv1 out)
static const size_t OFF_CRZ  = 75497472;   // [B][T] fp32 col 1/Z
static const size_t OFF_RS   = 75628544;   // [B][T] fp32 rowsum
static const size_t OFF_WX   = 75759616;   // [B][T] fp32 weight_x
static const size_t OFF_W1   = 75890688;   // [3][256][256] bf16 W1 [j][o][c]
static const size_t OFF_W2   = 76283904;   // [3][256][256] bf16 W2
static const size_t OFF_WQKV = 76677120;   // [384][256] bf16 (q|k|v) [n][c]

// ---------------------------------------------------------------------------
__global__ __launch_bounds__(256)
void wn_kernel(const float* __restrict__ v1, const float* __restrict__ g1,
               const float* __restrict__ v2, const float* __restrict__ g2,
               short* __restrict__ w1bf, short* __restrict__ w2bf) {
    __shared__ float red[4];
    int which = blockIdx.x >> 8, o = blockIdx.x & 255;
    const float* v = which ? v2 : v1;
    const float* g = which ? g2 : g1;
    short* wt = which ? w2bf : w1bf;
    const float* row = v + (size_t)o * 768;
    int tid = threadIdx.x, lane = tid & 63, wv_ = tid >> 6;
    float r0 = row[tid], r1 = row[tid + 256], r2 = row[tid + 512];
    float s = r0 * r0 + r1 * r1 + r2 * r2;
    for (int d = 1; d < 64; d <<= 1) s += __shfl_xor(s, d, 64);
    if (lane == 0) red[wv_] = s;
    __syncthreads();
    float scale = g[o] * rsqrtf(red[0] + red[1] + red[2] + red[3]);
    for (int j = 0; j < 3; ++j)
        wt[((size_t)(j * 256 + o)) * 256 + tid] = f2bf(scale * row[tid * 3 + j]);
}

__global__ __launch_bounds__(256)
void pack_kernel(const float* __restrict__ wq, const float* __restrict__ wk,
                 const float* __restrict__ wv, short* __restrict__ wqkvbf) {
    int n = blockIdx.x * 4 + (threadIdx.x >> 6);
    int c0 = (threadIdx.x & 63) * 4;
    for (int p = 0; p < 4; ++p) {
        int c = c0 + p;
        float w;
        if (n < 64)       w = wq[c * 64 + n];
        else if (n < 128) w = wk[c * 64 + n - 64];
        else              w = wv[c * 256 + n - 128];
        wqkvbf[(size_t)n * 256 + c] = f2bf(w);
    }
}

// ---------------------------------------------------------------------------
__global__ void transpose_kernel(const float* __restrict__ x, short* __restrict__ xt) {
    __shared__ float Tt[64 * 68];
    int tid = threadIdx.x;
    int c0 = blockIdx.x * 64, t0 = blockIdx.y * 64, b = blockIdx.z;
    for (int it = 0; it < 4; ++it) {
        int idx = tid + 256 * it;
        int cr = idx >> 4, tc = idx & 15;
        f4 v = *reinterpret_cast<const f4*>(&x[((size_t)b * CC + c0 + cr) * TT + t0 + tc * 4]);
        *reinterpret_cast<f4*>(&Tt[cr * 68 + tc * 4]) = v;
    }
    __syncthreads();
    for (int it = 0; it < 2; ++it) {
        int idx = tid + 256 * it;
        int tl = idx >> 3, seg = idx & 7;
        s8 o;
        for (int p = 0; p < 8; ++p) o[p] = f2bf(Tt[(seg * 8 + p) * 68 + tl]);
        *reinterpret_cast<s8*>(&xt[((size_t)b * TT + t0 + tl) * CC + c0 + seg * 8]) = o;
    }
}

// ---------------------------------------------------------------------------
// qkv: 1D grid 1536, bid = q*48 + n*8 + r -> same-A blocks same XCD.
// R22: register prefetch of the NEXT kc tile (A 4 regs + B 2 regs), issued
// right after the staging barrier so global latency hides under the MFMA
// section (same pattern that works in attn). Pure reordering.
__global__ __launch_bounds__(256, 3)
void qkv_kernel(const short* __restrict__ xt, const short* __restrict__ wqkv,
                const float* __restrict__ bq, const float* __restrict__ bk,
                const float* __restrict__ bv,
                short* __restrict__ qbf, short* __restrict__ kbf, short* __restrict__ vt) {
    __shared__ short SL[128 * 72 + 64 * 72];   // A (128t x 64c) then B (64n x 64c)
    short* Asm = SL;
    short* Bsm = SL + 128 * 72;
    int tid = threadIdx.x, wv_ = tid >> 6, lane = tid & 63;
    int n15 = lane & 15, quad = lane >> 4;
    int bid = blockIdx.x;
    int r = bid & 7, n = (bid >> 3) % 6, qd = bid / 48;
    int bt = qd * 8 + r;
    int b = bt >> 3, t0 = (bt & 7) * 128;
    int n0 = n * 64;

    f32x4 acc[2][4];
    for (int i = 0; i < 2; ++i) for (int j = 0; j < 4; ++j)
        for (int p = 0; p < 4; ++p) acc[i][j][p] = 0.f;

    s8 areg[4], breg[2];
    for (int it = 0; it < 4; ++it) {           // preload kc=0
        int idx = tid + 256 * it;
        int row = idx >> 3, seg = idx & 7;
        areg[it] = *reinterpret_cast<const s8*>(&xt[((size_t)b * TT + t0 + row) * CC + seg * 8]);
    }
    for (int it = 0; it < 2; ++it) {
        int idx = tid + 256 * it;
        int row = idx >> 3, seg = idx & 7;
        breg[it] = *reinterpret_cast<const s8*>(&wqkv[(size_t)(n0 + row) * 256 + seg * 8]);
    }

    for (int kc = 0; kc < 4; ++kc) {
        __syncthreads();
        for (int it = 0; it < 4; ++it) {
            int idx = tid + 256 * it;
            int row = idx >> 3, seg = idx & 7;
            *reinterpret_cast<s8*>(&Asm[row * 72 + seg * 8]) = areg[it];
        }
        for (int it = 0; it < 2; ++it) {
            int idx = tid + 256 * it;
            int row = idx >> 3, seg = idx & 7;
            *reinterpret_cast<s8*>(&Bsm[row * 72 + seg * 8]) = breg[it];
        }
        __syncthreads();
        if (kc < 3) {                          // prefetch kc+1 (hidden under MFMA)
            int c0n = (kc + 1) * 64;
            for (int it = 0; it < 4; ++it) {
                int idx = tid + 256 * it;
                int row = idx >> 3, seg = idx & 7;
                areg[it] = *reinterpret_cast<const s8*>(&xt[((size_t)b * TT + t0 + row) * CC + c0n + seg * 8]);
            }
            for (int it = 0; it < 2; ++it) {
                int idx = tid + 256 * it;
                int row = idx >> 3, seg = idx & 7;
                breg[it] = *reinterpret_cast<const s8*>(&wqkv[(size_t)(n0 + row) * 256 + c0n + seg * 8]);
            }
        }
        for (int ks = 0; ks < 2; ++ks)
            for (int mt2 = 0; mt2 < 2; ++mt2) {
                s8 a = *reinterpret_cast<const s8*>(&Asm[(wv_ * 32 + mt2 * 16 + n15) * 72 + quad * 8 + ks * 32]);
                for (int nt = 0; nt < 4; ++nt) {
                    s8 bb = *reinterpret_cast<const s8*>(&Bsm[(nt * 16 + n15) * 72 + quad * 8 + ks * 32]);
                    acc[mt2][nt] = __builtin_amdgcn_mfma_f32_16x16x32_bf16(a, bb, acc[mt2][nt], 0, 0, 0);
                }
            }
    }
    if (n0 < 128) {
        short* outp = (n0 == 0) ? qbf : kbf;
        const float* bias = (n0 == 0) ? bq : bk;
        for (int mt2 = 0; mt2 < 2; ++mt2)
            for (int nt = 0; nt < 4; ++nt) {
                int n_ = nt * 16 + n15;
                float bvl = bias[n_];
                for (int reg = 0; reg < 4; ++reg) {
                    int t = t0 + wv_ * 32 + mt2 * 16 + quad * 4 + reg;
                    outp[((size_t)b * TT + t) * 64 + n_] = f2bf(acc[mt2][nt][reg] + bvl);
                }
            }
    } else {
        int cbase = n0 - 128;
        __syncthreads();
        short* Tw = SL + wv_ * 3072;
        for (int mt2 = 0; mt2 < 2; ++mt2)
            for (int nt = 0; nt < 4; ++nt) {
                int n_ = nt * 16 + n15;
                float bvl = bv[cbase + n_];
                for (int reg = 0; reg < 4; ++reg)
                    Tw[n_ * 48 + mt2 * 16 + quad * 4 + reg] = f2bf(acc[mt2][nt][reg] + bvl);
            }
        for (int p = 0; p < 4; ++p) {
            int n_ = (lane >> 2) + 16 * p;
            int seg = lane & 3;
            s8 vv = *reinterpret_cast<const s8*>(&Tw[n_ * 48 + seg * 8]);
            *reinterpret_cast<s8*>(&vt[((size_t)b * CC + cbase + n_) * TT + t0 + wv_ * 32 + seg * 8]) = vv;
        }
    }
}

// ---------------------------------------------------------------------------
// colz: R17 version verbatim (proven config of the 225.8µs best total).
// 4-qt-wide units, 2 barriers per 4 qt, zero QK duplication. XCD decode
// b = bid&31.
__global__ __launch_bounds__(512, 2)
void colz_kernel(const short* __restrict__ qbf, const short* __restrict__ kbf,
                 float* __restrict__ colrz) {
    __shared__ short Qs[4][64 * 72];
    __shared__ short Ks[64 * 72];
    __shared__ float redz[8][2][32];
    int tid = threadIdx.x, wv_ = tid >> 6, lane = tid & 63;
    int l31 = lane & 31, lh = lane >> 5;
    int qh = wv_ & 1, ti = wv_ >> 1;     // q-half, qt-tile within unit
    int b = blockIdx.x & 31, pr = blockIdx.x >> 5;
    int kts[2] = {pr, 15 - pr};
    int row = tid >> 3, sg = (tid & 7) * 8;

    s8 kr = *reinterpret_cast<const s8*>(&kbf[((size_t)b * TT + kts[0] * 64 + row) * 64 + sg]);
    s8 qreg[4];
    for (int j = 0; j < 4; ++j) {
        int t = kts[0] + j; if (t > 15) t = 15;
        qreg[j] = *reinterpret_cast<const s8*>(&qbf[((size_t)b * TT + t * 64 + row) * 64 + sg]);
    }

    for (int ph = 0; ph < 2; ++ph) {
        int kt = kts[ph];
        float zl[2] = {0.f, 0.f};
        for (int u = kt; u < 16; u += 4) {
            __syncthreads();                       // B-top: Qs reuse safe
            if (u == kt) *reinterpret_cast<s8*>(&Ks[row * 72 + sg]) = kr;
            for (int j = 0; j < 4; ++j)
                *reinterpret_cast<s8*>(&Qs[j][row * 72 + sg]) = qreg[j];
            __syncthreads();                       // B-stage
            int nu = u + 4;
            if (nu < 16) {
                for (int j = 0; j < 4; ++j) {
                    int t = nu + j; if (t > 15) t = 15;
                    qreg[j] = *reinterpret_cast<const s8*>(&qbf[((size_t)b * TT + t * 64 + row) * 64 + sg]);
                }
            } else if (ph == 0) {
                int k2 = kts[1];
                kr = *reinterpret_cast<const s8*>(&kbf[((size_t)b * TT + k2 * 64 + row) * 64 + sg]);
                for (int j = 0; j < 4; ++j) {
                    int t = k2 + j; if (t > 15) t = 15;
                    qreg[j] = *reinterpret_cast<const s8*>(&qbf[((size_t)b * TT + t * 64 + row) * 64 + sg]);
                }
            }
            int qtw = u + ti;
            if (qtw < 16) {
                for (int kh = 0; kh < 2; ++kh) {
                    f32x16 s;
                    for (int p = 0; p < 16; ++p) s[p] = 0.f;
                    for (int kc = 0; kc < 4; ++kc) {
                        s8 a  = *reinterpret_cast<const s8*>(&Qs[ti][(qh * 32 + l31) * 72 + kc * 16 + lh * 8]);
                        s8 bb = *reinterpret_cast<const s8*>(&Ks[(kh * 32 + l31) * 72 + kc * 16 + lh * 8]);
                        s = __builtin_amdgcn_mfma_f32_32x32x16_bf16(a, bb, s, 0, 0, 0);
                    }
                    int kg = kt * 64 + kh * 32 + l31;
                    int qb0 = qtw * 64 + qh * 32 + 4 * lh;
                    if (qtw > kt) {
                        for (int reg = 0; reg < 16; ++reg)
                            zl[kh] += __expf(s[reg] * 0.125f);
                    } else {
                        for (int reg = 0; reg < 16; ++reg) {
                            int rr = (reg & 3) + 8 * (reg >> 2);
                            if (qb0 + rr >= kg) zl[kh] += __expf(s[reg] * 0.125f);
                        }
                    }
                }
            }
        }
        for (int kh = 0; kh < 2; ++kh) {
            float zc = zl[kh] + __shfl_xor(zl[kh], 32, 64);
            if (lane < 32) redz[wv_][kh][lane] = zc;
        }
        __syncthreads();
        if (tid < 64) {
            int kh = tid >> 5, kk = tid & 31;
            float Z = 0.f;
            for (int w = 0; w < 8; ++w) Z += redz[w][kh][kk];
            colrz[(size_t)b * TT + kt * 64 + tid] = 1.0f / Z;
        }
        __syncthreads();
    }
}

// ---------------------------------------------------------------------------
// attn: R17 version verbatim — the best measured attn config (47.3µs) of the
// 225.8µs total. 11 structural variants (R0..R21: staged/direct, 1-3
// barriers, 8/16 waves, co-residency, in-register P) all land at 47-52µs:
// declared a local ceiling; left untouched.
__global__ __launch_bounds__(512, 2)
void attn_kernel(const short* __restrict__ qbf, const short* __restrict__ kbf,
                 const short* __restrict__ vt, const float* __restrict__ colrz,
                 short* __restrict__ oab, float* __restrict__ rowsum) {
    __shared__ short Ks[2][64 * 72];
    __shared__ short Ps[2][64 * 72];
    __shared__ short Vs[2][256 * 72];
    __shared__ float redR[4][64];
    int tid = threadIdx.x, wv_ = tid >> 6, lane = tid & 63;
    int l31 = lane & 31, lh = lane >> 5;
    int wq2 = wv_ & 1;
    int wk4 = wv_ >> 1;          // 0..3
    int ksub = wk4 >> 1;         // QK: kt tile of the pair
    int kh2 = wk4 & 1;           // QK: k-half within tile
    int wcq = wv_ >> 1;          // PV: c quarter
    int b = blockIdx.x & 31, pr = blockIdx.x >> 5;
    int qts[2] = {15 - pr, pr};
    int row = tid >> 3, sg = (tid & 7) * 8;

    s8 kreg[2], vreg[2][4];
    for (int j = 0; j < 2; ++j) {      // prefetch tiles 0,1 (always valid memory)
        kreg[j] = *reinterpret_cast<const s8*>(&kbf[((size_t)b * TT + j * 64 + row) * 64 + sg]);
        for (int it = 0; it < 4; ++it) {
            int idx = tid + 512 * it;
            int vr = idx >> 3, seg = idx & 7;
            vreg[j][it] = *reinterpret_cast<const s8*>(&vt[((size_t)b * CC + vr) * TT + j * 64 + seg * 8]);
        }
    }

    for (int ph = 0; ph < 2; ++ph) {
        int qt = qts[ph];
        s8 qf[4];                      // Q fragment in registers (once per phase)
        for (int kc = 0; kc < 4; ++kc)
            qf[kc] = *reinterpret_cast<const s8*>(
                &qbf[((size_t)b * TT + qt * 64 + wq2 * 32 + l31) * 64 + kc * 16 + lh * 8]);
        f32x16 acc[2];
        for (int i = 0; i < 2; ++i) for (int p = 0; p < 16; ++p) acc[i][p] = 0.f;
        float rsum[16];
        for (int i = 0; i < 16; ++i) rsum[i] = 0.f;

        for (int kt = 0; kt <= qt; kt += 2) {
            bool two = (kt + 1 <= qt);
            __syncthreads();                       // B-top
            *reinterpret_cast<s8*>(&Ks[0][row * 72 + sg]) = kreg[0];
            if (two) *reinterpret_cast<s8*>(&Ks[1][row * 72 + sg]) = kreg[1];
            for (int it = 0; it < 4; ++it) {
                int idx = tid + 512 * it;
                int vr = idx >> 3, seg = idx & 7;
                *reinterpret_cast<s8*>(&Vs[0][vr * 72 + seg * 8]) = vreg[0][it];
                if (two) *reinterpret_cast<s8*>(&Vs[1][vr * 72 + seg * 8]) = vreg[1][it];
            }
            __syncthreads();                       // B-stage
            int nkt = (kt + 2 <= qt) ? kt + 2 : ((ph == 0) ? 0 : -1);
            if (nkt >= 0) {                        // prefetch next pair (nkt+1<=15: valid)
                for (int j = 0; j < 2; ++j) {
                    kreg[j] = *reinterpret_cast<const s8*>(&kbf[((size_t)b * TT + (nkt + j) * 64 + row) * 64 + sg]);
                    for (int it = 0; it < 4; ++it) {
                        int idx = tid + 512 * it;
                        int vr = idx >> 3, seg = idx & 7;
                        vreg[j][it] = *reinterpret_cast<const s8*>(&vt[((size_t)b * CC + vr) * TT + (nkt + j) * 64 + seg * 8]);
                    }
                }
            }
            // QK: wave's quadrant (wq2, kh2) of tile ksub — no duplication
            int mykt = kt + ksub;
            if (two || ksub == 0) {
                f32x16 s;
                for (int p = 0; p < 16; ++p) s[p] = 0.f;
                for (int kc = 0; kc < 4; ++kc) {
                    s8 bb = *reinterpret_cast<const s8*>(&Ks[ksub][(kh2 * 32 + l31) * 72 + kc * 16 + lh * 8]);
                    s = __builtin_amdgcn_mfma_f32_32x32x16_bf16(qf[kc], bb, s, 0, 0, 0);
                }
                int kg = mykt * 64 + kh2 * 32 + l31;
                float rz = colrz[(size_t)b * TT + kg];
                bool full = (mykt < qt);
                int qb0 = qt * 64 + wq2 * 32 + 4 * lh;
                for (int reg = 0; reg < 16; ++reg) {
                    int rr = (reg & 3) + 8 * (reg >> 2);
                    float p = 0.f;
                    if (full || qb0 + rr >= kg) p = __expf(s[reg] * 0.125f) * rz;
                    rsum[reg] += p;
                    Ps[ksub][(wq2 * 32 + rr + 4 * lh) * 72 + kh2 * 32 + l31] = f2bf(p);
                }
            }
            __syncthreads();                       // B-Ps
            // PV: wave (wq2, wcq), both kt tiles (tile 1 gated in remainder)
            int jmax = two ? 2 : 1;
            for (int j = 0; j < jmax; ++j)
                for (int kc = 0; kc < 4; ++kc) {
                    s8 a = *reinterpret_cast<const s8*>(&Ps[j][(wq2 * 32 + l31) * 72 + kc * 16 + lh * 8]);
                    for (int nt = 0; nt < 2; ++nt) {
                        s8 bb = *reinterpret_cast<const s8*>(&Vs[j][(wcq * 64 + nt * 32 + l31) * 72 + kc * 16 + lh * 8]);
                        acc[nt] = __builtin_amdgcn_mfma_f32_32x32x16_bf16(a, bb, acc[nt], 0, 0, 0);
                    }
                }
        }
        // rowsum: butterfly over 32 k-lanes; combine 4 k-slices via redR
        for (int reg = 0; reg < 16; ++reg) {
            float v = rsum[reg];
            v += __shfl_xor(v, 1, 64);
            v += __shfl_xor(v, 2, 64);
            v += __shfl_xor(v, 4, 64);
            v += __shfl_xor(v, 8, 64);
            v += __shfl_xor(v, 16, 64);
            int rr = (reg & 3) + 8 * (reg >> 2);
            if (l31 == 0) redR[wk4][wq2 * 32 + rr + 4 * lh] = v;
        }
        for (int nt = 0; nt < 2; ++nt) {
            int c = wcq * 64 + nt * 32 + l31;
            for (int reg = 0; reg < 16; ++reg) {
                int q = qt * 64 + wq2 * 32 + (reg & 3) + 8 * (reg >> 2) + 4 * lh;
                oab[((size_t)b * TT + q) * CC + c] = f2bf(acc[nt][reg]);
            }
        }
        __syncthreads();
        if (tid < 64)
            rowsum[(size_t)b * TT + qt * 64 + tid] =
                redR[0][tid] + redR[1][tid] + redR[2][tid] + redR[3][tid];
        __syncthreads();
    }
}

// ---------------------------------------------------------------------------
// conv: 1D grid 1024, bid = q*32 + n0*8 + r (same-A blocks same XCD).
// R22: register prefetch of the NEXT kc tile (A 5 regs + B 6 regs) issued
// after the staging barrier -> global latency hides under the MFMA section
// instead of sitting exposed between the two barriers (4x per block).
// R10: optional fused final epilogue (conv2): out[b,c,t] = relu(c2 + x*(1+wx))
// via LDS transpose — c2 (32 MB fp32) never touches HBM.
__global__ __launch_bounds__(256, 3)
void conv_kernel(const void* __restrict__ inp, int in_is_fp32,
                 const short* __restrict__ wbf, const float* __restrict__ bias,
                 void* __restrict__ outp, int out_is_bf16,
                 const float* __restrict__ xres, const float* __restrict__ wxv,
                 int fuse_final) {
    __shared__ short SL[130 * 72 + 3 * 64 * 72];   // As | Bs ; reused as Ft[128][67] fp32
    short* As = SL;
    short* Bs = SL + 130 * 72;
    int tid = threadIdx.x, wv_ = tid >> 6, lane = tid & 63;
    int n15 = lane & 15, quad = lane >> 4;
    int bid = blockIdx.x;
    int r = bid & 7;
    int n0 = ((bid >> 3) & 3) << 6;
    int bm = (bid >> 5) * 8 + r;
    int b = bm >> 3, mt = bm & 7;
    int t0 = mt * 128;
    f32x4 acc[2][4];
    for (int i = 0; i < 2; ++i) for (int j = 0; j < 4; ++j)
        for (int p = 0; p < 4; ++p) acc[i][j][p] = 0.f;

    s8 aregs[5], bregs[6];
    if (!in_is_fp32) {                 // preload kc=0 A tile into regs
        const short* in = (const short*)inp;
        for (int it = 0; it < 5; ++it) {
            int idx = tid + 256 * it;
            int row = idx >> 3, seg = idx & 7;
            if (row < 130) {
                int t = t0 + row - 2;
                s8 st;
                if (t >= 0) st = *reinterpret_cast<const s8*>(&in[((size_t)b * TT + t) * CC + seg * 8]);
                else for (int p = 0; p < 8; ++p) st[p] = 0;
                aregs[it] = st;
            }
        }
    }
    for (int it = 0; it < 6; ++it) {   // preload kc=0 B tile into regs
        int idx = tid + 256 * it;
        int row = idx >> 3, seg = idx & 7;
        int j = row >> 6, o = row & 63;
        bregs[it] = *reinterpret_cast<const s8*>(&wbf[((size_t)(j * 256 + n0 + o)) * 256 + seg * 8]);
    }

    for (int kc = 0; kc < 4; ++kc) {
        int c0 = kc * 64;
        __syncthreads();
        if (in_is_fp32) {
            const float* in = (const float*)inp;
            for (int it = 0; it < 9; ++it) {
                int idx = tid + 256 * it;
                int row = idx >> 4, fc = idx & 15;
                if (row < 130) {
                    int t = t0 + row - 2;
                    s4v st;
                    if (t >= 0) {
                        f4 v = *reinterpret_cast<const f4*>(&in[((size_t)b * TT + t) * CC + c0 + fc * 4]);
                        for (int p = 0; p < 4; ++p) st[p] = f2bf(v[p]);
                    } else { for (int p = 0; p < 4; ++p) st[p] = 0; }
                    *reinterpret_cast<s4v*>(&As[row * 72 + fc * 4]) = st;
                }
            }
        } else {
            for (int it = 0; it < 5; ++it) {
                int idx = tid + 256 * it;
                int row = idx >> 3, seg = idx & 7;
                if (row < 130)
                    *reinterpret_cast<s8*>(&As[row * 72 + seg * 8]) = aregs[it];
            }
        }
        for (int it = 0; it < 6; ++it) {
            int idx = tid + 256 * it;
            int row = idx >> 3, seg = idx & 7;
            *reinterpret_cast<s8*>(&Bs[row * 72 + seg * 8]) = bregs[it];
        }
        __syncthreads();
        if (kc < 3) {                  // prefetch kc+1 (hidden under MFMA below)
            int c0n = c0 + 64;
            if (!in_is_fp32) {
                const short* in = (const short*)inp;
                for (int it = 0; it < 5; ++it) {
                    int idx = tid + 256 * it;
                    int row = idx >> 3, seg = idx & 7;
                    if (row < 130) {
                        int t = t0 + row - 2;
                        s8 st;
                        if (t >= 0) st = *reinterpret_cast<const s8*>(&in[((size_t)b * TT + t) * CC + c0n + seg * 8]);
                        else for (int p = 0; p < 8; ++p) st[p] = 0;
                        aregs[it] = st;
                    }
                }
            }
            for (int it = 0; it < 6; ++it) {
                int idx = tid + 256 * it;
                int row = idx >> 3, seg = idx & 7;
                int j = row >> 6, o = row & 63;
                bregs[it] = *reinterpret_cast<const s8*>(&wbf[((size_t)(j * 256 + n0 + o)) * 256 + c0n + seg * 8]);
            }
        }
        for (int j = 0; j < 3; ++j)
            for (int ks = 0; ks < 2; ++ks)
                for (int mt2 = 0; mt2 < 2; ++mt2) {
                    s8 a = *reinterpret_cast<const s8*>(&As[(wv_ * 32 + mt2 * 16 + n15 + j) * 72 + quad * 8 + ks * 32]);
                    for (int nt = 0; nt < 4; ++nt) {
                        s8 bb = *reinterpret_cast<const s8*>(&Bs[(j * 64 + nt * 16 + n15) * 72 + quad * 8 + ks * 32]);
                        acc[mt2][nt] = __builtin_amdgcn_mfma_f32_16x16x32_bf16(a, bb, acc[mt2][nt], 0, 0, 0);
                    }
                }
    }
    if (!fuse_final) {
        for (int mt2 = 0; mt2 < 2; ++mt2)
            for (int nt = 0; nt < 4; ++nt) {
                int o = n0 + nt * 16 + n15;
                float bvl = bias[o];
                for (int reg = 0; reg < 4; ++reg) {
                    int t = t0 + wv_ * 32 + mt2 * 16 + quad * 4 + reg;
                    float v = fmaxf(acc[mt2][nt][reg] + bvl, 0.f);
                    if (out_is_bf16) ((short*)outp)[((size_t)b * TT + t) * CC + o] = f2bf(v);
                    else             ((float*)outp)[((size_t)b * TT + t) * CC + o] = v;
                }
            }
    } else {
        float* Ft = (float*)SL;            // [128][67] fp32 (34304 B <= SL)
        __syncthreads();                   // all LDS reads of As/Bs done
        for (int mt2 = 0; mt2 < 2; ++mt2)
            for (int nt = 0; nt < 4; ++nt) {
                int ol = nt * 16 + n15;
                float bvl = bias[n0 + ol];
                for (int reg = 0; reg < 4; ++reg) {
                    int tl = wv_ * 32 + mt2 * 16 + quad * 4 + reg;
                    Ft[tl * 67 + ol] = fmaxf(acc[mt2][nt][reg] + bvl, 0.f);
                }
            }
        __syncthreads();
        int c_l = tid >> 5;                // 0..7
        int t_l = (tid & 31) * 4;          // 0..124
        f4 wv4 = *reinterpret_cast<const f4*>(&wxv[(size_t)b * TT + t0 + t_l]);
        for (int pass = 0; pass < 8; ++pass) {
            int c = n0 + pass * 8 + c_l;
            f4 xv = *reinterpret_cast<const f4*>(&xres[((size_t)b * CC + c) * TT + t0 + t_l]);
            f4 rr;
            for (int p = 0; p < 4; ++p)
                rr[p] = fmaxf(Ft[(t_l + p) * 67 + pass * 8 + c_l] + xv[p] * (1.f + wv4[p]), 0.f);
            *reinterpret_cast<f4*>(&((float*)outp)[((size_t)b * CC + c) * TT + t0 + t_l]) = rr;
        }
    }
}

// ---------------------------------------------------------------------------
__global__ void rowsm_kernel(const float* __restrict__ rowsum, float* __restrict__ wx) {
    __shared__ float red[256];
    int b = blockIdx.x, tid = threadIdx.x;
    float v[4];
    float m = -1e30f;
    for (int r = 0; r < 4; ++r) { v[r] = rowsum[(size_t)b * TT + tid + 256 * r]; m = fmaxf(m, v[r]); }
    red[tid] = m; __syncthreads();
    for (int s = 128; s > 0; s >>= 1) { if (tid < s) red[tid] = fmaxf(red[tid], red[tid + s]); __syncthreads(); }
    m = red[0]; __syncthreads();
    float e[4], zs = 0.f;
    for (int r = 0; r < 4; ++r) { e[r] = __expf(v[r] - m); zs += e[r]; }
    red[tid] = zs; __syncthreads();
    for (int s = 128; s > 0; s >>= 1) { if (tid < s) red[tid] += red[tid + s]; __syncthreads(); }
    float rz = 1.0f / red[0];
    for (int r = 0; r < 4; ++r) wx[(size_t)b * TT + tid + 256 * r] = e[r] * rz;
}

// ---------------------------------------------------------------------------
extern "C" void kernel_launch(void* const* d_in, const int* in_sizes, int n_in,
                              void* d_out, int out_size, void* d_ws, size_t ws_size,
                              hipStream_t stream) {
    (void)in_sizes; (void)n_in; (void)out_size; (void)ws_size;
    const float* x  = (const float*)d_in[0];
    const float* wq = (const float*)d_in[1];
    const float* bq = (const float*)d_in[2];
    const float* wk = (const float*)d_in[3];
    const float* bk = (const float*)d_in[4];
    const float* wv = (const float*)d_in[5];
    const float* bv = (const float*)d_in[6];
    const float* v1 = (const float*)d_in[7];
    const float* g1 = (const float*)d_in[8];
    const float* b1 = (const float*)d_in[9];
    const float* v2 = (const float*)d_in[10];
    const float* g2 = (const float*)d_in[11];
    const float* b2 = (const float*)d_in[12];
    char* ws = (char*)d_ws;
    float* out = (float*)d_out;

    short* qbf  = (short*)(ws + OFF_QBF);
    short* kbf  = (short*)(ws + OFF_KBF);
    short* vt   = (short*)(ws + OFF_VT);
    short* xt   = (short*)(ws + OFF_OA);   // xt bf16 (dead after qkv)
    short* oab  = (short*)(ws + OFF_OA);   // oa bf16 (attn out; dead after conv1)
    short* c1   = (short*)(ws + OFF_C1);
    float* crz  = (float*)(ws + OFF_CRZ);
    float* rs   = (float*)(ws + OFF_RS);
    float* wxb  = (float*)(ws + OFF_WX);
    short* w1bf = (short*)(ws + OFF_W1);
    short* w2bf = (short*)(ws + OFF_W2);
    short* wqkv = (short*)(ws + OFF_WQKV);

    wn_kernel<<<dim3(512), dim3(256), 0, stream>>>(v1, g1, v2, g2, w1bf, w2bf);
    pack_kernel<<<dim3(96), dim3(256), 0, stream>>>(wq, wk, wv, wqkv);
    transpose_kernel<<<dim3(4, 16, 32), dim3(256), 0, stream>>>(x, xt);
    qkv_kernel<<<dim3(1536), dim3(256), 0, stream>>>(xt, wqkv, bq, bk, bv, qbf, kbf, vt);
    colz_kernel<<<dim3(256), dim3(512), 0, stream>>>(qbf, kbf, crz);
    attn_kernel<<<dim3(256), dim3(512), 0, stream>>>(qbf, kbf, vt, crz, oab, rs);
    rowsm_kernel<<<dim3(32), dim3(256), 0, stream>>>(rs, wxb);
    conv_kernel<<<dim3(1024), dim3(256), 0, stream>>>(oab, 0, w1bf, b1, c1, 1,
                                                      nullptr, nullptr, 0);
    conv_kernel<<<dim3(1024), dim3(256), 0, stream>>>(c1, 0, w2bf, b2, out, 0,
                                                      x, wxb, 1);
}

// Round 13
// 216.688 us; speedup vs baseline: 1.1412x; 1.0159x over previous
//
#include <hip/hip_runtime.h>
#include <math.h>

#define BB 32
#define CC 256
#define TT 1024

typedef __attribute__((ext_vector_type(4))) float f4;
typedef __attribute__((ext_vector_type(4))) float f32x4;
typedef __attribute__((ext_vector_type(16))) float f32x16;
typedef __attribute__((ext_vector_type(8))) short s8;   // bf16x8 MFMA frag (4 VGPRs)
typedef __attribute__((ext_vector_type(4))) short s4v;  // 8B LDS store

__device__ inline short f2bf(float f) {                 // RNE fp32->bf16
    unsigned u = __builtin_bit_cast(unsigned, f);
    u = (u + 0x7FFFu + ((u >> 16) & 1u)) >> 16;
    return (short)u;
}

// ---- workspace layout (bytes) ----
static const size_t OFF_QBF  = 0;          // [B][T][64] bf16   4 MB
static const size_t OFF_KBF  = 4194304;    // [B][T][64] bf16   4 MB
static const size_t OFF_VT   = 8388608;    // [B][C][T]  bf16  16 MB (v transposed)
static const size_t OFF_OA   = 25165824;   // [B][T][C]: xt bf16 -> oa bf16 (16 MB used of 32)
static const size_t OFF_C1   = 58720256;   // [B][T][C]  bf16  16 MB (conv1 out)
static const size_t OFF_CRZ  = 75497472;   // [B][T] fp32 col 1/Z
static const size_t OFF_RS   = 75628544;   // [B][T] fp32 rowsum
static const size_t OFF_WX   = 75759616;   // [B][T] fp32 weight_x
static const size_t OFF_W1   = 75890688;   // [3][256][256] bf16 W1 [j][o][c]
static const size_t OFF_W2   = 76283904;   // [3][256][256] bf16 W2
static const size_t OFF_WQKV = 76677120;   // [384][256] bf16 (q|k|v) [n][c]

// ---------------------------------------------------------------------------
// R23: wn + pack fused into one launch (grid 608: 512 wn-blocks, 96 pack).
__global__ __launch_bounds__(256)
void wnpack_kernel(const float* __restrict__ v1, const float* __restrict__ g1,
                   const float* __restrict__ v2, const float* __restrict__ g2,
                   const float* __restrict__ wq, const float* __restrict__ wk,
                   const float* __restrict__ wv,
                   short* __restrict__ w1bf, short* __restrict__ w2bf,
                   short* __restrict__ wqkvbf) {
    __shared__ float red[4];
    int bid = blockIdx.x;
    if (bid < 512) {
        int which = bid >> 8, o = bid & 255;
        const float* v = which ? v2 : v1;
        const float* g = which ? g2 : g1;
        short* wt = which ? w2bf : w1bf;
        const float* row = v + (size_t)o * 768;
        int tid = threadIdx.x, lane = tid & 63, wv_ = tid >> 6;
        float r0 = row[tid], r1 = row[tid + 256], r2 = row[tid + 512];
        float s = r0 * r0 + r1 * r1 + r2 * r2;
        for (int d = 1; d < 64; d <<= 1) s += __shfl_xor(s, d, 64);
        if (lane == 0) red[wv_] = s;
        __syncthreads();
        float scale = g[o] * rsqrtf(red[0] + red[1] + red[2] + red[3]);
        for (int j = 0; j < 3; ++j)
            wt[((size_t)(j * 256 + o)) * 256 + tid] = f2bf(scale * row[tid * 3 + j]);
    } else {
        int pb = bid - 512;
        int n = pb * 4 + (threadIdx.x >> 6);
        int c0 = (threadIdx.x & 63) * 4;
        for (int p = 0; p < 4; ++p) {
            int c = c0 + p;
            float w;
            if (n < 64)       w = wq[c * 64 + n];
            else if (n < 128) w = wk[c * 64 + n - 64];
            else              w = wv[c * 256 + n - 128];
            wqkvbf[(size_t)n * 256 + c] = f2bf(w);
        }
    }
}

// ---------------------------------------------------------------------------
__global__ void transpose_kernel(const float* __restrict__ x, short* __restrict__ xt) {
    __shared__ float Tt[64 * 68];
    int tid = threadIdx.x;
    int c0 = blockIdx.x * 64, t0 = blockIdx.y * 64, b = blockIdx.z;
    for (int it = 0; it < 4; ++it) {
        int idx = tid + 256 * it;
        int cr = idx >> 4, tc = idx & 15;
        f4 v = *reinterpret_cast<const f4*>(&x[((size_t)b * CC + c0 + cr) * TT + t0 + tc * 4]);
        *reinterpret_cast<f4*>(&Tt[cr * 68 + tc * 4]) = v;
    }
    __syncthreads();
    for (int it = 0; it < 2; ++it) {
        int idx = tid + 256 * it;
        int tl = idx >> 3, seg = idx & 7;
        s8 o;
        for (int p = 0; p < 8; ++p) o[p] = f2bf(Tt[(seg * 8 + p) * 68 + tl]);
        *reinterpret_cast<s8*>(&xt[((size_t)b * TT + t0 + tl) * CC + c0 + seg * 8]) = o;
    }
}

// ---------------------------------------------------------------------------
// qkv: 1D grid 1536, bid = q*48 + n*8 + r -> same-A blocks same XCD.
// R22: register prefetch of the NEXT kc tile. R23: B-frag LDS reads hoisted
// out of the mt2 loop (explicit CSE: 10 -> 6 ds_read_b128 per ks).
__global__ __launch_bounds__(256, 3)
void qkv_kernel(const short* __restrict__ xt, const short* __restrict__ wqkv,
                const float* __restrict__ bq, const float* __restrict__ bk,
                const float* __restrict__ bv,
                short* __restrict__ qbf, short* __restrict__ kbf, short* __restrict__ vt) {
    __shared__ short SL[128 * 72 + 64 * 72];   // A (128t x 64c) then B (64n x 64c)
    short* Asm = SL;
    short* Bsm = SL + 128 * 72;
    int tid = threadIdx.x, wv_ = tid >> 6, lane = tid & 63;
    int n15 = lane & 15, quad = lane >> 4;
    int bid = blockIdx.x;
    int r = bid & 7, n = (bid >> 3) % 6, qd = bid / 48;
    int bt = qd * 8 + r;
    int b = bt >> 3, t0 = (bt & 7) * 128;
    int n0 = n * 64;

    f32x4 acc[2][4];
    for (int i = 0; i < 2; ++i) for (int j = 0; j < 4; ++j)
        for (int p = 0; p < 4; ++p) acc[i][j][p] = 0.f;

    s8 areg[4], breg[2];
    for (int it = 0; it < 4; ++it) {           // preload kc=0
        int idx = tid + 256 * it;
        int row = idx >> 3, seg = idx & 7;
        areg[it] = *reinterpret_cast<const s8*>(&xt[((size_t)b * TT + t0 + row) * CC + seg * 8]);
    }
    for (int it = 0; it < 2; ++it) {
        int idx = tid + 256 * it;
        int row = idx >> 3, seg = idx & 7;
        breg[it] = *reinterpret_cast<const s8*>(&wqkv[(size_t)(n0 + row) * 256 + seg * 8]);
    }

    for (int kc = 0; kc < 4; ++kc) {
        __syncthreads();
        for (int it = 0; it < 4; ++it) {
            int idx = tid + 256 * it;
            int row = idx >> 3, seg = idx & 7;
            *reinterpret_cast<s8*>(&Asm[row * 72 + seg * 8]) = areg[it];
        }
        for (int it = 0; it < 2; ++it) {
            int idx = tid + 256 * it;
            int row = idx >> 3, seg = idx & 7;
            *reinterpret_cast<s8*>(&Bsm[row * 72 + seg * 8]) = breg[it];
        }
        __syncthreads();
        if (kc < 3) {                          // prefetch kc+1 (hidden under MFMA)
            int c0n = (kc + 1) * 64;
            for (int it = 0; it < 4; ++it) {
                int idx = tid + 256 * it;
                int row = idx >> 3, seg = idx & 7;
                areg[it] = *reinterpret_cast<const s8*>(&xt[((size_t)b * TT + t0 + row) * CC + c0n + seg * 8]);
            }
            for (int it = 0; it < 2; ++it) {
                int idx = tid + 256 * it;
                int row = idx >> 3, seg = idx & 7;
                breg[it] = *reinterpret_cast<const s8*>(&wqkv[(size_t)(n0 + row) * 256 + c0n + seg * 8]);
            }
        }
        for (int ks = 0; ks < 2; ++ks) {
            s8 bfr[4];
            for (int nt = 0; nt < 4; ++nt)
                bfr[nt] = *reinterpret_cast<const s8*>(&Bsm[(nt * 16 + n15) * 72 + quad * 8 + ks * 32]);
            for (int mt2 = 0; mt2 < 2; ++mt2) {
                s8 a = *reinterpret_cast<const s8*>(&Asm[(wv_ * 32 + mt2 * 16 + n15) * 72 + quad * 8 + ks * 32]);
                for (int nt = 0; nt < 4; ++nt)
                    acc[mt2][nt] = __builtin_amdgcn_mfma_f32_16x16x32_bf16(a, bfr[nt], acc[mt2][nt], 0, 0, 0);
            }
        }
    }
    if (n0 < 128) {
        short* outp = (n0 == 0) ? qbf : kbf;
        const float* bias = (n0 == 0) ? bq : bk;
        for (int mt2 = 0; mt2 < 2; ++mt2)
            for (int nt = 0; nt < 4; ++nt) {
                int n_ = nt * 16 + n15;
                float bvl = bias[n_];
                for (int reg = 0; reg < 4; ++reg) {
                    int t = t0 + wv_ * 32 + mt2 * 16 + quad * 4 + reg;
                    outp[((size_t)b * TT + t) * 64 + n_] = f2bf(acc[mt2][nt][reg] + bvl);
                }
            }
    } else {
        int cbase = n0 - 128;
        __syncthreads();
        short* Tw = SL + wv_ * 3072;
        for (int mt2 = 0; mt2 < 2; ++mt2)
            for (int nt = 0; nt < 4; ++nt) {
                int n_ = nt * 16 + n15;
                float bvl = bv[cbase + n_];
                for (int reg = 0; reg < 4; ++reg)
                    Tw[n_ * 48 + mt2 * 16 + quad * 4 + reg] = f2bf(acc[mt2][nt][reg] + bvl);
            }
        for (int p = 0; p < 4; ++p) {
            int n_ = (lane >> 2) + 16 * p;
            int seg = lane & 3;
            s8 vv = *reinterpret_cast<const s8*>(&Tw[n_ * 48 + seg * 8]);
            *reinterpret_cast<s8*>(&vt[((size_t)b * CC + cbase + n_) * TT + t0 + wv_ * 32 + seg * 8]) = vv;
        }
    }
}

// ---------------------------------------------------------------------------
// colz: R17 version verbatim (proven config). 4-qt-wide units, 2 barriers
// per 4 qt, zero QK duplication. XCD decode b = bid&31.
__global__ __launch_bounds__(512, 2)
void colz_kernel(const short* __restrict__ qbf, const short* __restrict__ kbf,
                 float* __restrict__ colrz) {
    __shared__ short Qs[4][64 * 72];
    __shared__ short Ks[64 * 72];
    __shared__ float redz[8][2][32];
    int tid = threadIdx.x, wv_ = tid >> 6, lane = tid & 63;
    int l31 = lane & 31, lh = lane >> 5;
    int qh = wv_ & 1, ti = wv_ >> 1;     // q-half, qt-tile within unit
    int b = blockIdx.x & 31, pr = blockIdx.x >> 5;
    int kts[2] = {pr, 15 - pr};
    int row = tid >> 3, sg = (tid & 7) * 8;

    s8 kr = *reinterpret_cast<const s8*>(&kbf[((size_t)b * TT + kts[0] * 64 + row) * 64 + sg]);
    s8 qreg[4];
    for (int j = 0; j < 4; ++j) {
        int t = kts[0] + j; if (t > 15) t = 15;
        qreg[j] = *reinterpret_cast<const s8*>(&qbf[((size_t)b * TT + t * 64 + row) * 64 + sg]);
    }

    for (int ph = 0; ph < 2; ++ph) {
        int kt = kts[ph];
        float zl[2] = {0.f, 0.f};
        for (int u = kt; u < 16; u += 4) {
            __syncthreads();                       // B-top: Qs reuse safe
            if (u == kt) *reinterpret_cast<s8*>(&Ks[row * 72 + sg]) = kr;
            for (int j = 0; j < 4; ++j)
                *reinterpret_cast<s8*>(&Qs[j][row * 72 + sg]) = qreg[j];
            __syncthreads();                       // B-stage
            int nu = u + 4;
            if (nu < 16) {
                for (int j = 0; j < 4; ++j) {
                    int t = nu + j; if (t > 15) t = 15;
                    qreg[j] = *reinterpret_cast<const s8*>(&qbf[((size_t)b * TT + t * 64 + row) * 64 + sg]);
                }
            } else if (ph == 0) {
                int k2 = kts[1];
                kr = *reinterpret_cast<const s8*>(&kbf[((size_t)b * TT + k2 * 64 + row) * 64 + sg]);
                for (int j = 0; j < 4; ++j) {
                    int t = k2 + j; if (t > 15) t = 15;
                    qreg[j] = *reinterpret_cast<const s8*>(&qbf[((size_t)b * TT + t * 64 + row) * 64 + sg]);
                }
            }
            int qtw = u + ti;
            if (qtw < 16) {
                for (int kh = 0; kh < 2; ++kh) {
                    f32x16 s;
                    for (int p = 0; p < 16; ++p) s[p] = 0.f;
                    for (int kc = 0; kc < 4; ++kc) {
                        s8 a  = *reinterpret_cast<const s8*>(&Qs[ti][(qh * 32 + l31) * 72 + kc * 16 + lh * 8]);
                        s8 bb = *reinterpret_cast<const s8*>(&Ks[(kh * 32 + l31) * 72 + kc * 16 + lh * 8]);
                        s = __builtin_amdgcn_mfma_f32_32x32x16_bf16(a, bb, s, 0, 0, 0);
                    }
                    int kg = kt * 64 + kh * 32 + l31;
                    int qb0 = qtw * 64 + qh * 32 + 4 * lh;
                    if (qtw > kt) {
                        for (int reg = 0; reg < 16; ++reg)
                            zl[kh] += __expf(s[reg] * 0.125f);
                    } else {
                        for (int reg = 0; reg < 16; ++reg) {
                            int rr = (reg & 3) + 8 * (reg >> 2);
                            if (qb0 + rr >= kg) zl[kh] += __expf(s[reg] * 0.125f);
                        }
                    }
                }
            }
        }
        for (int kh = 0; kh < 2; ++kh) {
            float zc = zl[kh] + __shfl_xor(zl[kh], 32, 64);
            if (lane < 32) redz[wv_][kh][lane] = zc;
        }
        __syncthreads();
        if (tid < 64) {
            int kh = tid >> 5, kk = tid & 31;
            float Z = 0.f;
            for (int w = 0; w < 8; ++w) Z += redz[w][kh][kk];
            colrz[(size_t)b * TT + kt * 64 + tid] = 1.0f / Z;
        }
        __syncthreads();
    }
}

// ---------------------------------------------------------------------------
// attn: R17 version verbatim — best measured attn config. 11 structural
// variants (R0..R21) all landed 47-52µs: declared local ceiling; untouched.
__global__ __launch_bounds__(512, 2)
void attn_kernel(const short* __restrict__ qbf, const short* __restrict__ kbf,
                 const short* __restrict__ vt, const float* __restrict__ colrz,
                 short* __restrict__ oab, float* __restrict__ rowsum) {
    __shared__ short Ks[2][64 * 72];
    __shared__ short Ps[2][64 * 72];
    __shared__ short Vs[2][256 * 72];
    __shared__ float redR[4][64];
    int tid = threadIdx.x, wv_ = tid >> 6, lane = tid & 63;
    int l31 = lane & 31, lh = lane >> 5;
    int wq2 = wv_ & 1;
    int wk4 = wv_ >> 1;          // 0..3
    int ksub = wk4 >> 1;         // QK: kt tile of the pair
    int kh2 = wk4 & 1;           // QK: k-half within tile
    int wcq = wv_ >> 1;          // PV: c quarter
    int b = blockIdx.x & 31, pr = blockIdx.x >> 5;
    int qts[2] = {15 - pr, pr};
    int row = tid >> 3, sg = (tid & 7) * 8;

    s8 kreg[2], vreg[2][4];
    for (int j = 0; j < 2; ++j) {      // prefetch tiles 0,1 (always valid memory)
        kreg[j] = *reinterpret_cast<const s8*>(&kbf[((size_t)b * TT + j * 64 + row) * 64 + sg]);
        for (int it = 0; it < 4; ++it) {
            int idx = tid + 512 * it;
            int vr = idx >> 3, seg = idx & 7;
            vreg[j][it] = *reinterpret_cast<const s8*>(&vt[((size_t)b * CC + vr) * TT + j * 64 + seg * 8]);
        }
    }

    for (int ph = 0; ph < 2; ++ph) {
        int qt = qts[ph];
        s8 qf[4];                      // Q fragment in registers (once per phase)
        for (int kc = 0; kc < 4; ++kc)
            qf[kc] = *reinterpret_cast<const s8*>(
                &qbf[((size_t)b * TT + qt * 64 + wq2 * 32 + l31) * 64 + kc * 16 + lh * 8]);
        f32x16 acc[2];
        for (int i = 0; i < 2; ++i) for (int p = 0; p < 16; ++p) acc[i][p] = 0.f;
        float rsum[16];
        for (int i = 0; i < 16; ++i) rsum[i] = 0.f;

        for (int kt = 0; kt <= qt; kt += 2) {
            bool two = (kt + 1 <= qt);
            __syncthreads();                       // B-top
            *reinterpret_cast<s8*>(&Ks[0][row * 72 + sg]) = kreg[0];
            if (two) *reinterpret_cast<s8*>(&Ks[1][row * 72 + sg]) = kreg[1];
            for (int it = 0; it < 4; ++it) {
                int idx = tid + 512 * it;
                int vr = idx >> 3, seg = idx & 7;
                *reinterpret_cast<s8*>(&Vs[0][vr * 72 + seg * 8]) = vreg[0][it];
                if (two) *reinterpret_cast<s8*>(&Vs[1][vr * 72 + seg * 8]) = vreg[1][it];
            }
            __syncthreads();                       // B-stage
            int nkt = (kt + 2 <= qt) ? kt + 2 : ((ph == 0) ? 0 : -1);
            if (nkt >= 0) {                        // prefetch next pair (nkt+1<=15: valid)
                for (int j = 0; j < 2; ++j) {
                    kreg[j] = *reinterpret_cast<const s8*>(&kbf[((size_t)b * TT + (nkt + j) * 64 + row) * 64 + sg]);
                    for (int it = 0; it < 4; ++it) {
                        int idx = tid + 512 * it;
                        int vr = idx >> 3, seg = idx & 7;
                        vreg[j][it] = *reinterpret_cast<const s8*>(&vt[((size_t)b * CC + vr) * TT + (nkt + j) * 64 + seg * 8]);
                    }
                }
            }
            // QK: wave's quadrant (wq2, kh2) of tile ksub — no duplication
            int mykt = kt + ksub;
            if (two || ksub == 0) {
                f32x16 s;
                for (int p = 0; p < 16; ++p) s[p] = 0.f;
                for (int kc = 0; kc < 4; ++kc) {
                    s8 bb = *reinterpret_cast<const s8*>(&Ks[ksub][(kh2 * 32 + l31) * 72 + kc * 16 + lh * 8]);
                    s = __builtin_amdgcn_mfma_f32_32x32x16_bf16(qf[kc], bb, s, 0, 0, 0);
                }
                int kg = mykt * 64 + kh2 * 32 + l31;
                float rz = colrz[(size_t)b * TT + kg];
                bool full = (mykt < qt);
                int qb0 = qt * 64 + wq2 * 32 + 4 * lh;
                for (int reg = 0; reg < 16; ++reg) {
                    int rr = (reg & 3) + 8 * (reg >> 2);
                    float p = 0.f;
                    if (full || qb0 + rr >= kg) p = __expf(s[reg] * 0.125f) * rz;
                    rsum[reg] += p;
                    Ps[ksub][(wq2 * 32 + rr + 4 * lh) * 72 + kh2 * 32 + l31] = f2bf(p);
                }
            }
            __syncthreads();                       // B-Ps
            // PV: wave (wq2, wcq), both kt tiles (tile 1 gated in remainder)
            int jmax = two ? 2 : 1;
            for (int j = 0; j < jmax; ++j)
                for (int kc = 0; kc < 4; ++kc) {
                    s8 a = *reinterpret_cast<const s8*>(&Ps[j][(wq2 * 32 + l31) * 72 + kc * 16 + lh * 8]);
                    for (int nt = 0; nt < 2; ++nt) {
                        s8 bb = *reinterpret_cast<const s8*>(&Vs[j][(wcq * 64 + nt * 32 + l31) * 72 + kc * 16 + lh * 8]);
                        acc[nt] = __builtin_amdgcn_mfma_f32_32x32x16_bf16(a, bb, acc[nt], 0, 0, 0);
                    }
                }
        }
        // rowsum: butterfly over 32 k-lanes; combine 4 k-slices via redR
        for (int reg = 0; reg < 16; ++reg) {
            float v = rsum[reg];
            v += __shfl_xor(v, 1, 64);
            v += __shfl_xor(v, 2, 64);
            v += __shfl_xor(v, 4, 64);
            v += __shfl_xor(v, 8, 64);
            v += __shfl_xor(v, 16, 64);
            int rr = (reg & 3) + 8 * (reg >> 2);
            if (l31 == 0) redR[wk4][wq2 * 32 + rr + 4 * lh] = v;
        }
        for (int nt = 0; nt < 2; ++nt) {
            int c = wcq * 64 + nt * 32 + l31;
            for (int reg = 0; reg < 16; ++reg) {
                int q = qt * 64 + wq2 * 32 + (reg & 3) + 8 * (reg >> 2) + 4 * lh;
                oab[((size_t)b * TT + q) * CC + c] = f2bf(acc[nt][reg]);
            }
        }
        __syncthreads();
        if (tid < 64)
            rowsum[(size_t)b * TT + qt * 64 + tid] =
                redR[0][tid] + redR[1][tid] + redR[2][tid] + redR[3][tid];
        __syncthreads();
    }
}

// ---------------------------------------------------------------------------
// conv: 1D grid 1024(+32), bid = q*32 + n0*8 + r (same-A blocks same XCD).
// R22: register prefetch of the NEXT kc tile. R23: (a) B-frag LDS reads
// hoisted out of mt2 (10 -> 6 ds_read_b128 per (j,ks)); (b) rowsm absorbed
// as 32 extra blocks in the conv1 launch (they run the reduction and return
// before any conv barrier; stream order guarantees wx ready for conv2).
// R10: optional fused final epilogue (conv2): out[b,c,t] = relu(c2+x*(1+wx)).
__global__ __launch_bounds__(256, 3)
void conv_kernel(const void* __restrict__ inp, int in_is_fp32,
                 const short* __restrict__ wbf, const float* __restrict__ bias,
                 void* __restrict__ outp, int out_is_bf16,
                 const float* __restrict__ xres, const float* __restrict__ wxv,
                 int fuse_final,
                 const float* __restrict__ rsin, float* __restrict__ wxout) {
    __shared__ short SL[130 * 72 + 3 * 64 * 72];   // As | Bs ; reused as Ft / rowsm-red
    short* As = SL;
    short* Bs = SL + 130 * 72;
    int tid = threadIdx.x, wv_ = tid >> 6, lane = tid & 63;
    int n15 = lane & 15, quad = lane >> 4;
    int bid = blockIdx.x;
    if (rsin != nullptr && bid >= 1024) {          // rowsm side-task blocks
        float* red = (float*)SL;
        int b2 = bid - 1024;
        float v[4];
        float m = -1e30f;
        for (int r2 = 0; r2 < 4; ++r2) {
            v[r2] = rsin[(size_t)b2 * TT + tid + 256 * r2];
            m = fmaxf(m, v[r2]);
        }
        red[tid] = m; __syncthreads();
        for (int s2 = 128; s2 > 0; s2 >>= 1) { if (tid < s2) red[tid] = fmaxf(red[tid], red[tid + s2]); __syncthreads(); }
        m = red[0]; __syncthreads();
        float e[4], zs = 0.f;
        for (int r2 = 0; r2 < 4; ++r2) { e[r2] = __expf(v[r2] - m); zs += e[r2]; }
        red[tid] = zs; __syncthreads();
        for (int s2 = 128; s2 > 0; s2 >>= 1) { if (tid < s2) red[tid] += red[tid + s2]; __syncthreads(); }
        float rz2 = 1.0f / red[0];
        for (int r2 = 0; r2 < 4; ++r2) wxout[(size_t)b2 * TT + tid + 256 * r2] = e[r2] * rz2;
        return;
    }
    int r = bid & 7;
    int n0 = ((bid >> 3) & 3) << 6;
    int bm = (bid >> 5) * 8 + r;
    int b = bm >> 3, mt = bm & 7;
    int t0 = mt * 128;
    f32x4 acc[2][4];
    for (int i = 0; i < 2; ++i) for (int j = 0; j < 4; ++j)
        for (int p = 0; p < 4; ++p) acc[i][j][p] = 0.f;

    s8 aregs[5], bregs[6];
    if (!in_is_fp32) {                 // preload kc=0 A tile into regs
        const short* in = (const short*)inp;
        for (int it = 0; it < 5; ++it) {
            int idx = tid + 256 * it;
            int row = idx >> 3, seg = idx & 7;
            if (row < 130) {
                int t = t0 + row - 2;
                s8 st;
                if (t >= 0) st = *reinterpret_cast<const s8*>(&in[((size_t)b * TT + t) * CC + seg * 8]);
                else for (int p = 0; p < 8; ++p) st[p] = 0;
                aregs[it] = st;
            }
        }
    }
    for (int it = 0; it < 6; ++it) {   // preload kc=0 B tile into regs
        int idx = tid + 256 * it;
        int row = idx >> 3, seg = idx & 7;
        int j = row >> 6, o = row & 63;
        bregs[it] = *reinterpret_cast<const s8*>(&wbf[((size_t)(j * 256 + n0 + o)) * 256 + seg * 8]);
    }

    for (int kc = 0; kc < 4; ++kc) {
        int c0 = kc * 64;
        __syncthreads();
        if (in_is_fp32) {
            const float* in = (const float*)inp;
            for (int it = 0; it < 9; ++it) {
                int idx = tid + 256 * it;
                int row = idx >> 4, fc = idx & 15;
                if (row < 130) {
                    int t = t0 + row - 2;
                    s4v st;
                    if (t >= 0) {
                        f4 v = *reinterpret_cast<const f4*>(&in[((size_t)b * TT + t) * CC + c0 + fc * 4]);
                        for (int p = 0; p < 4; ++p) st[p] = f2bf(v[p]);
                    } else { for (int p = 0; p < 4; ++p) st[p] = 0; }
                    *reinterpret_cast<s4v*>(&As[row * 72 + fc * 4]) = st;
                }
            }
        } else {
            for (int it = 0; it < 5; ++it) {
                int idx = tid + 256 * it;
                int row = idx >> 3, seg = idx & 7;
                if (row < 130)
                    *reinterpret_cast<s8*>(&As[row * 72 + seg * 8]) = aregs[it];
            }
        }
        for (int it = 0; it < 6; ++it) {
            int idx = tid + 256 * it;
            int row = idx >> 3, seg = idx & 7;
            *reinterpret_cast<s8*>(&Bs[row * 72 + seg * 8]) = bregs[it];
        }
        __syncthreads();
        if (kc < 3) {                  // prefetch kc+1 (hidden under MFMA below)
            int c0n = c0 + 64;
            if (!in_is_fp32) {
                const short* in = (const short*)inp;
                for (int it = 0; it < 5; ++it) {
                    int idx = tid + 256 * it;
                    int row = idx >> 3, seg = idx & 7;
                    if (row < 130) {
                        int t = t0 + row - 2;
                        s8 st;
                        if (t >= 0) st = *reinterpret_cast<const s8*>(&in[((size_t)b * TT + t) * CC + c0n + seg * 8]);
                        else for (int p = 0; p < 8; ++p) st[p] = 0;
                        aregs[it] = st;
                    }
                }
            }
            for (int it = 0; it < 6; ++it) {
                int idx = tid + 256 * it;
                int row = idx >> 3, seg = idx & 7;
                int j = row >> 6, o = row & 63;
                bregs[it] = *reinterpret_cast<const s8*>(&wbf[((size_t)(j * 256 + n0 + o)) * 256 + c0n + seg * 8]);
            }
        }
        for (int j = 0; j < 3; ++j)
            for (int ks = 0; ks < 2; ++ks) {
                s8 bfr[4];
                for (int nt = 0; nt < 4; ++nt)
                    bfr[nt] = *reinterpret_cast<const s8*>(&Bs[(j * 64 + nt * 16 + n15) * 72 + quad * 8 + ks * 32]);
                for (int mt2 = 0; mt2 < 2; ++mt2) {
                    s8 a = *reinterpret_cast<const s8*>(&As[(wv_ * 32 + mt2 * 16 + n15 + j) * 72 + quad * 8 + ks * 32]);
                    for (int nt = 0; nt < 4; ++nt)
                        acc[mt2][nt] = __builtin_amdgcn_mfma_f32_16x16x32_bf16(a, bfr[nt], acc[mt2][nt], 0, 0, 0);
                }
            }
    }
    if (!fuse_final) {
        for (int mt2 = 0; mt2 < 2; ++mt2)
            for (int nt = 0; nt < 4; ++nt) {
                int o = n0 + nt * 16 + n15;
                float bvl = bias[o];
                for (int reg = 0; reg < 4; ++reg) {
                    int t = t0 + wv_ * 32 + mt2 * 16 + quad * 4 + reg;
                    float v = fmaxf(acc[mt2][nt][reg] + bvl, 0.f);
                    if (out_is_bf16) ((short*)outp)[((size_t)b * TT + t) * CC + o] = f2bf(v);
                    else             ((float*)outp)[((size_t)b * TT + t) * CC + o] = v;
                }
            }
    } else {
        float* Ft = (float*)SL;            // [128][67] fp32 (34304 B <= SL)
        __syncthreads();                   // all LDS reads of As/Bs done
        for (int mt2 = 0; mt2 < 2; ++mt2)
            for (int nt = 0; nt < 4; ++nt) {
                int ol = nt * 16 + n15;
                float bvl = bias[n0 + ol];
                for (int reg = 0; reg < 4; ++reg) {
                    int tl = wv_ * 32 + mt2 * 16 + quad * 4 + reg;
                    Ft[tl * 67 + ol] = fmaxf(acc[mt2][nt][reg] + bvl, 0.f);
                }
            }
        __syncthreads();
        int c_l = tid >> 5;                // 0..7
        int t_l = (tid & 31) * 4;          // 0..124
        f4 wv4 = *reinterpret_cast<const f4*>(&wxv[(size_t)b * TT + t0 + t_l]);
        for (int pass = 0; pass < 8; ++pass) {
            int c = n0 + pass * 8 + c_l;
            f4 xv = *reinterpret_cast<const f4*>(&xres[((size_t)b * CC + c) * TT + t0 + t_l]);
            f4 rr;
            for (int p = 0; p < 4; ++p)
                rr[p] = fmaxf(Ft[(t_l + p) * 67 + pass * 8 + c_l] + xv[p] * (1.f + wv4[p]), 0.f);
            *reinterpret_cast<f4*>(&((float*)outp)[((size_t)b * CC + c) * TT + t0 + t_l]) = rr;
        }
    }
}

// ---------------------------------------------------------------------------
extern "C" void kernel_launch(void* const* d_in, const int* in_sizes, int n_in,
                              void* d_out, int out_size, void* d_ws, size_t ws_size,
                              hipStream_t stream) {
    (void)in_sizes; (void)n_in; (void)out_size; (void)ws_size;
    const float* x  = (const float*)d_in[0];
    const float* wq = (const float*)d_in[1];
    const float* bq = (const float*)d_in[2];
    const float* wk = (const float*)d_in[3];
    const float* bk = (const float*)d_in[4];
    const float* wv = (const float*)d_in[5];
    const float* bv = (const float*)d_in[6];
    const float* v1 = (const float*)d_in[7];
    const float* g1 = (const float*)d_in[8];
    const float* b1 = (const float*)d_in[9];
    const float* v2 = (const float*)d_in[10];
    const float* g2 = (const float*)d_in[11];
    const float* b2 = (const float*)d_in[12];
    char* ws = (char*)d_ws;
    float* out = (float*)d_out;

    short* qbf  = (short*)(ws + OFF_QBF);
    short* kbf  = (short*)(ws + OFF_KBF);
    short* vt   = (short*)(ws + OFF_VT);
    short* xt   = (short*)(ws + OFF_OA);   // xt bf16 (dead after qkv)
    short* oab  = (short*)(ws + OFF_OA);   // oa bf16 (attn out; dead after conv1)
    short* c1   = (short*)(ws + OFF_C1);
    float* crz  = (float*)(ws + OFF_CRZ);
    float* rs   = (float*)(ws + OFF_RS);
    float* wxb  = (float*)(ws + OFF_WX);
    short* w1bf = (short*)(ws + OFF_W1);
    short* w2bf = (short*)(ws + OFF_W2);
    short* wqkv = (short*)(ws + OFF_WQKV);

    wnpack_kernel<<<dim3(608), dim3(256), 0, stream>>>(v1, g1, v2, g2, wq, wk, wv,
                                                       w1bf, w2bf, wqkv);
    transpose_kernel<<<dim3(4, 16, 32), dim3(256), 0, stream>>>(x, xt);
    qkv_kernel<<<dim3(1536), dim3(256), 0, stream>>>(xt, wqkv, bq, bk, bv, qbf, kbf, vt);
    colz_kernel<<<dim3(256), dim3(512), 0, stream>>>(qbf, kbf, crz);
    attn_kernel<<<dim3(256), dim3(512), 0, stream>>>(qbf, kbf, vt, crz, oab, rs);
    conv_kernel<<<dim3(1056), dim3(256), 0, stream>>>(oab, 0, w1bf, b1, c1, 1,
                                                      nullptr, nullptr, 0, rs, wxb);
    conv_kernel<<<dim3(1024), dim3(256), 0, stream>>>(c1, 0, w2bf, b2, out, 0,
                                                      x, wxb, 1, nullptr, nullptr);
}

// Round 14
// 210.607 us; speedup vs baseline: 1.1741x; 1.0289x over previous
//
#include <hip/hip_runtime.h>
#include <math.h>

#define BB 32
#define CC 256
#define TT 1024

typedef __attribute__((ext_vector_type(4))) float f4;
typedef __attribute__((ext_vector_type(4))) float f32x4;
typedef __attribute__((ext_vector_type(16))) float f32x16;
typedef __attribute__((ext_vector_type(8))) short s8;   // bf16x8 MFMA frag (4 VGPRs)
typedef __attribute__((ext_vector_type(4))) short s4v;  // 8B LDS store

__device__ inline short f2bf(float f) {                 // RNE fp32->bf16
    unsigned u = __builtin_bit_cast(unsigned, f);
    u = (u + 0x7FFFu + ((u >> 16) & 1u)) >> 16;
    return (short)u;
}

// ---- workspace layout (bytes) ----
static const size_t OFF_QBF  = 0;          // [B][T][64] bf16   4 MB
static const size_t OFF_KBF  = 4194304;    // [B][T][64] bf16   4 MB
static const size_t OFF_VT   = 8388608;    // [B][C][T]  bf16  16 MB (v transposed)
static const size_t OFF_OA   = 25165824;   // [B][T][C]: xt bf16 -> oa bf16 (16 MB used of 32)
static const size_t OFF_C1   = 58720256;   // [B][T][C]  bf16  16 MB (conv1 out)
static const size_t OFF_CRZ  = 75497472;   // [B][T] fp32 col 1/Z
static const size_t OFF_RS   = 75628544;   // [B][T] fp32 rowsum
static const size_t OFF_WX   = 75759616;   // [B][T] fp32 weight_x
static const size_t OFF_W1   = 75890688;   // [3][256][256] bf16 W1 [j][o][c]
static const size_t OFF_W2   = 76283904;   // [3][256][256] bf16 W2
static const size_t OFF_WQKV = 76677120;   // [384][256] bf16 (q|k|v) [n][c]

// ---------------------------------------------------------------------------
// R23: wn + pack fused into one launch (grid 608: 512 wn-blocks, 96 pack).
__global__ __launch_bounds__(256)
void wnpack_kernel(const float* __restrict__ v1, const float* __restrict__ g1,
                   const float* __restrict__ v2, const float* __restrict__ g2,
                   const float* __restrict__ wq, const float* __restrict__ wk,
                   const float* __restrict__ wv,
                   short* __restrict__ w1bf, short* __restrict__ w2bf,
                   short* __restrict__ wqkvbf) {
    __shared__ float red[4];
    int bid = blockIdx.x;
    if (bid < 512) {
        int which = bid >> 8, o = bid & 255;
        const float* v = which ? v2 : v1;
        const float* g = which ? g2 : g1;
        short* wt = which ? w2bf : w1bf;
        const float* row = v + (size_t)o * 768;
        int tid = threadIdx.x, lane = tid & 63, wv_ = tid >> 6;
        float r0 = row[tid], r1 = row[tid + 256], r2 = row[tid + 512];
        float s = r0 * r0 + r1 * r1 + r2 * r2;
        for (int d = 1; d < 64; d <<= 1) s += __shfl_xor(s, d, 64);
        if (lane == 0) red[wv_] = s;
        __syncthreads();
        float scale = g[o] * rsqrtf(red[0] + red[1] + red[2] + red[3]);
        for (int j = 0; j < 3; ++j)
            wt[((size_t)(j * 256 + o)) * 256 + tid] = f2bf(scale * row[tid * 3 + j]);
    } else {
        int pb = bid - 512;
        int n = pb * 4 + (threadIdx.x >> 6);
        int c0 = (threadIdx.x & 63) * 4;
        for (int p = 0; p < 4; ++p) {
            int c = c0 + p;
            float w;
            if (n < 64)       w = wq[c * 64 + n];
            else if (n < 128) w = wk[c * 64 + n - 64];
            else              w = wv[c * 256 + n - 128];
            wqkvbf[(size_t)n * 256 + c] = f2bf(w);
        }
    }
}

// ---------------------------------------------------------------------------
__global__ void transpose_kernel(const float* __restrict__ x, short* __restrict__ xt) {
    __shared__ float Tt[64 * 68];
    int tid = threadIdx.x;
    int c0 = blockIdx.x * 64, t0 = blockIdx.y * 64, b = blockIdx.z;
    for (int it = 0; it < 4; ++it) {
        int idx = tid + 256 * it;
        int cr = idx >> 4, tc = idx & 15;
        f4 v = *reinterpret_cast<const f4*>(&x[((size_t)b * CC + c0 + cr) * TT + t0 + tc * 4]);
        *reinterpret_cast<f4*>(&Tt[cr * 68 + tc * 4]) = v;
    }
    __syncthreads();
    for (int it = 0; it < 2; ++it) {
        int idx = tid + 256 * it;
        int tl = idx >> 3, seg = idx & 7;
        s8 o;
        for (int p = 0; p < 8; ++p) o[p] = f2bf(Tt[(seg * 8 + p) * 68 + tl]);
        *reinterpret_cast<s8*>(&xt[((size_t)b * TT + t0 + tl) * CC + c0 + seg * 8]) = o;
    }
}

// ---------------------------------------------------------------------------
// qkv: 1D grid 1536, bid = q*48 + n*8 + r -> same-A blocks same XCD.
// R22: register prefetch of the NEXT kc tile. R23: B-frag LDS reads hoisted
// out of the mt2 loop (explicit CSE: 10 -> 6 ds_read_b128 per ks).
__global__ __launch_bounds__(256, 3)
void qkv_kernel(const short* __restrict__ xt, const short* __restrict__ wqkv,
                const float* __restrict__ bq, const float* __restrict__ bk,
                const float* __restrict__ bv,
                short* __restrict__ qbf, short* __restrict__ kbf, short* __restrict__ vt) {
    __shared__ short SL[128 * 72 + 64 * 72];   // A (128t x 64c) then B (64n x 64c)
    short* Asm = SL;
    short* Bsm = SL + 128 * 72;
    int tid = threadIdx.x, wv_ = tid >> 6, lane = tid & 63;
    int n15 = lane & 15, quad = lane >> 4;
    int bid = blockIdx.x;
    int r = bid & 7, n = (bid >> 3) % 6, qd = bid / 48;
    int bt = qd * 8 + r;
    int b = bt >> 3, t0 = (bt & 7) * 128;
    int n0 = n * 64;

    f32x4 acc[2][4];
    for (int i = 0; i < 2; ++i) for (int j = 0; j < 4; ++j)
        for (int p = 0; p < 4; ++p) acc[i][j][p] = 0.f;

    s8 areg[4], breg[2];
    for (int it = 0; it < 4; ++it) {           // preload kc=0
        int idx = tid + 256 * it;
        int row = idx >> 3, seg = idx & 7;
        areg[it] = *reinterpret_cast<const s8*>(&xt[((size_t)b * TT + t0 + row) * CC + seg * 8]);
    }
    for (int it = 0; it < 2; ++it) {
        int idx = tid + 256 * it;
        int row = idx >> 3, seg = idx & 7;
        breg[it] = *reinterpret_cast<const s8*>(&wqkv[(size_t)(n0 + row) * 256 + seg * 8]);
    }

    for (int kc = 0; kc < 4; ++kc) {
        __syncthreads();
        for (int it = 0; it < 4; ++it) {
            int idx = tid + 256 * it;
            int row = idx >> 3, seg = idx & 7;
            *reinterpret_cast<s8*>(&Asm[row * 72 + seg * 8]) = areg[it];
        }
        for (int it = 0; it < 2; ++it) {
            int idx = tid + 256 * it;
            int row = idx >> 3, seg = idx & 7;
            *reinterpret_cast<s8*>(&Bsm[row * 72 + seg * 8]) = breg[it];
        }
        __syncthreads();
        if (kc < 3) {                          // prefetch kc+1 (hidden under MFMA)
            int c0n = (kc + 1) * 64;
            for (int it = 0; it < 4; ++it) {
                int idx = tid + 256 * it;
                int row = idx >> 3, seg = idx & 7;
                areg[it] = *reinterpret_cast<const s8*>(&xt[((size_t)b * TT + t0 + row) * CC + c0n + seg * 8]);
            }
            for (int it = 0; it < 2; ++it) {
                int idx = tid + 256 * it;
                int row = idx >> 3, seg = idx & 7;
                breg[it] = *reinterpret_cast<const s8*>(&wqkv[(size_t)(n0 + row) * 256 + c0n + seg * 8]);
            }
        }
        for (int ks = 0; ks < 2; ++ks) {
            s8 bfr[4];
            for (int nt = 0; nt < 4; ++nt)
                bfr[nt] = *reinterpret_cast<const s8*>(&Bsm[(nt * 16 + n15) * 72 + quad * 8 + ks * 32]);
            for (int mt2 = 0; mt2 < 2; ++mt2) {
                s8 a = *reinterpret_cast<const s8*>(&Asm[(wv_ * 32 + mt2 * 16 + n15) * 72 + quad * 8 + ks * 32]);
                for (int nt = 0; nt < 4; ++nt)
                    acc[mt2][nt] = __builtin_amdgcn_mfma_f32_16x16x32_bf16(a, bfr[nt], acc[mt2][nt], 0, 0, 0);
            }
        }
    }
    if (n0 < 128) {
        short* outp = (n0 == 0) ? qbf : kbf;
        const float* bias = (n0 == 0) ? bq : bk;
        for (int mt2 = 0; mt2 < 2; ++mt2)
            for (int nt = 0; nt < 4; ++nt) {
                int n_ = nt * 16 + n15;
                float bvl = bias[n_];
                for (int reg = 0; reg < 4; ++reg) {
                    int t = t0 + wv_ * 32 + mt2 * 16 + quad * 4 + reg;
                    outp[((size_t)b * TT + t) * 64 + n_] = f2bf(acc[mt2][nt][reg] + bvl);
                }
            }
    } else {
        int cbase = n0 - 128;
        __syncthreads();
        short* Tw = SL + wv_ * 3072;
        for (int mt2 = 0; mt2 < 2; ++mt2)
            for (int nt = 0; nt < 4; ++nt) {
                int n_ = nt * 16 + n15;
                float bvl = bv[cbase + n_];
                for (int reg = 0; reg < 4; ++reg)
                    Tw[n_ * 48 + mt2 * 16 + quad * 4 + reg] = f2bf(acc[mt2][nt][reg] + bvl);
            }
        for (int p = 0; p < 4; ++p) {
            int n_ = (lane >> 2) + 16 * p;
            int seg = lane & 3;
            s8 vv = *reinterpret_cast<const s8*>(&Tw[n_ * 48 + seg * 8]);
            *reinterpret_cast<s8*>(&vt[((size_t)b * CC + cbase + n_) * TT + t0 + wv_ * 32 + seg * 8]) = vv;
        }
    }
}

// ---------------------------------------------------------------------------
// colz: R17 version verbatim (proven config). 4-qt-wide units, 2 barriers
// per 4 qt, zero QK duplication. XCD decode b = bid&31.
__global__ __launch_bounds__(512, 2)
void colz_kernel(const short* __restrict__ qbf, const short* __restrict__ kbf,
                 float* __restrict__ colrz) {
    __shared__ short Qs[4][64 * 72];
    __shared__ short Ks[64 * 72];
    __shared__ float redz[8][2][32];
    int tid = threadIdx.x, wv_ = tid >> 6, lane = tid & 63;
    int l31 = lane & 31, lh = lane >> 5;
    int qh = wv_ & 1, ti = wv_ >> 1;     // q-half, qt-tile within unit
    int b = blockIdx.x & 31, pr = blockIdx.x >> 5;
    int kts[2] = {pr, 15 - pr};
    int row = tid >> 3, sg = (tid & 7) * 8;

    s8 kr = *reinterpret_cast<const s8*>(&kbf[((size_t)b * TT + kts[0] * 64 + row) * 64 + sg]);
    s8 qreg[4];
    for (int j = 0; j < 4; ++j) {
        int t = kts[0] + j; if (t > 15) t = 15;
        qreg[j] = *reinterpret_cast<const s8*>(&qbf[((size_t)b * TT + t * 64 + row) * 64 + sg]);
    }

    for (int ph = 0; ph < 2; ++ph) {
        int kt = kts[ph];
        float zl[2] = {0.f, 0.f};
        for (int u = kt; u < 16; u += 4) {
            __syncthreads();                       // B-top: Qs reuse safe
            if (u == kt) *reinterpret_cast<s8*>(&Ks[row * 72 + sg]) = kr;
            for (int j = 0; j < 4; ++j)
                *reinterpret_cast<s8*>(&Qs[j][row * 72 + sg]) = qreg[j];
            __syncthreads();                       // B-stage
            int nu = u + 4;
            if (nu < 16) {
                for (int j = 0; j < 4; ++j) {
                    int t = nu + j; if (t > 15) t = 15;
                    qreg[j] = *reinterpret_cast<const s8*>(&qbf[((size_t)b * TT + t * 64 + row) * 64 + sg]);
                }
            } else if (ph == 0) {
                int k2 = kts[1];
                kr = *reinterpret_cast<const s8*>(&kbf[((size_t)b * TT + k2 * 64 + row) * 64 + sg]);
                for (int j = 0; j < 4; ++j) {
                    int t = k2 + j; if (t > 15) t = 15;
                    qreg[j] = *reinterpret_cast<const s8*>(&qbf[((size_t)b * TT + t * 64 + row) * 64 + sg]);
                }
            }
            int qtw = u + ti;
            if (qtw < 16) {
                for (int kh = 0; kh < 2; ++kh) {
                    f32x16 s;
                    for (int p = 0; p < 16; ++p) s[p] = 0.f;
                    for (int kc = 0; kc < 4; ++kc) {
                        s8 a  = *reinterpret_cast<const s8*>(&Qs[ti][(qh * 32 + l31) * 72 + kc * 16 + lh * 8]);
                        s8 bb = *reinterpret_cast<const s8*>(&Ks[(kh * 32 + l31) * 72 + kc * 16 + lh * 8]);
                        s = __builtin_amdgcn_mfma_f32_32x32x16_bf16(a, bb, s, 0, 0, 0);
                    }
                    int kg = kt * 64 + kh * 32 + l31;
                    int qb0 = qtw * 64 + qh * 32 + 4 * lh;
                    if (qtw > kt) {
                        for (int reg = 0; reg < 16; ++reg)
                            zl[kh] += __expf(s[reg] * 0.125f);
                    } else {
                        for (int reg = 0; reg < 16; ++reg) {
                            int rr = (reg & 3) + 8 * (reg >> 2);
                            if (qb0 + rr >= kg) zl[kh] += __expf(s[reg] * 0.125f);
                        }
                    }
                }
            }
        }
        for (int kh = 0; kh < 2; ++kh) {
            float zc = zl[kh] + __shfl_xor(zl[kh], 32, 64);
            if (lane < 32) redz[wv_][kh][lane] = zc;
        }
        __syncthreads();
        if (tid < 64) {
            int kh = tid >> 5, kk = tid & 31;
            float Z = 0.f;
            for (int w = 0; w < 8; ++w) Z += redz[w][kh][kk];
            colrz[(size_t)b * TT + kt * 64 + tid] = 1.0f / Z;
        }
        __syncthreads();
    }
}

// ---------------------------------------------------------------------------
// attn: R17 version verbatim — best measured attn config. 11 structural
// variants (R0..R21) all landed 47-52µs: declared local ceiling; untouched.
__global__ __launch_bounds__(512, 2)
void attn_kernel(const short* __restrict__ qbf, const short* __restrict__ kbf,
                 const short* __restrict__ vt, const float* __restrict__ colrz,
                 short* __restrict__ oab, float* __restrict__ rowsum) {
    __shared__ short Ks[2][64 * 72];
    __shared__ short Ps[2][64 * 72];
    __shared__ short Vs[2][256 * 72];
    __shared__ float redR[4][64];
    int tid = threadIdx.x, wv_ = tid >> 6, lane = tid & 63;
    int l31 = lane & 31, lh = lane >> 5;
    int wq2 = wv_ & 1;
    int wk4 = wv_ >> 1;          // 0..3
    int ksub = wk4 >> 1;         // QK: kt tile of the pair
    int kh2 = wk4 & 1;           // QK: k-half within tile
    int wcq = wv_ >> 1;          // PV: c quarter
    int b = blockIdx.x & 31, pr = blockIdx.x >> 5;
    int qts[2] = {15 - pr, pr};
    int row = tid >> 3, sg = (tid & 7) * 8;

    s8 kreg[2], vreg[2][4];
    for (int j = 0; j < 2; ++j) {      // prefetch tiles 0,1 (always valid memory)
        kreg[j] = *reinterpret_cast<const s8*>(&kbf[((size_t)b * TT + j * 64 + row) * 64 + sg]);
        for (int it = 0; it < 4; ++it) {
            int idx = tid + 512 * it;
            int vr = idx >> 3, seg = idx & 7;
            vreg[j][it] = *reinterpret_cast<const s8*>(&vt[((size_t)b * CC + vr) * TT + j * 64 + seg * 8]);
        }
    }

    for (int ph = 0; ph < 2; ++ph) {
        int qt = qts[ph];
        s8 qf[4];                      // Q fragment in registers (once per phase)
        for (int kc = 0; kc < 4; ++kc)
            qf[kc] = *reinterpret_cast<const s8*>(
                &qbf[((size_t)b * TT + qt * 64 + wq2 * 32 + l31) * 64 + kc * 16 + lh * 8]);
        f32x16 acc[2];
        for (int i = 0; i < 2; ++i) for (int p = 0; p < 16; ++p) acc[i][p] = 0.f;
        float rsum[16];
        for (int i = 0; i < 16; ++i) rsum[i] = 0.f;

        for (int kt = 0; kt <= qt; kt += 2) {
            bool two = (kt + 1 <= qt);
            __syncthreads();                       // B-top
            *reinterpret_cast<s8*>(&Ks[0][row * 72 + sg]) = kreg[0];
            if (two) *reinterpret_cast<s8*>(&Ks[1][row * 72 + sg]) = kreg[1];
            for (int it = 0; it < 4; ++it) {
                int idx = tid + 512 * it;
                int vr = idx >> 3, seg = idx & 7;
                *reinterpret_cast<s8*>(&Vs[0][vr * 72 + seg * 8]) = vreg[0][it];
                if (two) *reinterpret_cast<s8*>(&Vs[1][vr * 72 + seg * 8]) = vreg[1][it];
            }
            __syncthreads();                       // B-stage
            int nkt = (kt + 2 <= qt) ? kt + 2 : ((ph == 0) ? 0 : -1);
            if (nkt >= 0) {                        // prefetch next pair (nkt+1<=15: valid)
                for (int j = 0; j < 2; ++j) {
                    kreg[j] = *reinterpret_cast<const s8*>(&kbf[((size_t)b * TT + (nkt + j) * 64 + row) * 64 + sg]);
                    for (int it = 0; it < 4; ++it) {
                        int idx = tid + 512 * it;
                        int vr = idx >> 3, seg = idx & 7;
                        vreg[j][it] = *reinterpret_cast<const s8*>(&vt[((size_t)b * CC + vr) * TT + (nkt + j) * 64 + seg * 8]);
                    }
                }
            }
            // QK: wave's quadrant (wq2, kh2) of tile ksub — no duplication
            int mykt = kt + ksub;
            if (two || ksub == 0) {
                f32x16 s;
                for (int p = 0; p < 16; ++p) s[p] = 0.f;
                for (int kc = 0; kc < 4; ++kc) {
                    s8 bb = *reinterpret_cast<const s8*>(&Ks[ksub][(kh2 * 32 + l31) * 72 + kc * 16 + lh * 8]);
                    s = __builtin_amdgcn_mfma_f32_32x32x16_bf16(qf[kc], bb, s, 0, 0, 0);
                }
                int kg = mykt * 64 + kh2 * 32 + l31;
                float rz = colrz[(size_t)b * TT + kg];
                bool full = (mykt < qt);
                int qb0 = qt * 64 + wq2 * 32 + 4 * lh;
                for (int reg = 0; reg < 16; ++reg) {
                    int rr = (reg & 3) + 8 * (reg >> 2);
                    float p = 0.f;
                    if (full || qb0 + rr >= kg) p = __expf(s[reg] * 0.125f) * rz;
                    rsum[reg] += p;
                    Ps[ksub][(wq2 * 32 + rr + 4 * lh) * 72 + kh2 * 32 + l31] = f2bf(p);
                }
            }
            __syncthreads();                       // B-Ps
            // PV: wave (wq2, wcq), both kt tiles (tile 1 gated in remainder)
            int jmax = two ? 2 : 1;
            for (int j = 0; j < jmax; ++j)
                for (int kc = 0; kc < 4; ++kc) {
                    s8 a = *reinterpret_cast<const s8*>(&Ps[j][(wq2 * 32 + l31) * 72 + kc * 16 + lh * 8]);
                    for (int nt = 0; nt < 2; ++nt) {
                        s8 bb = *reinterpret_cast<const s8*>(&Vs[j][(wcq * 64 + nt * 32 + l31) * 72 + kc * 16 + lh * 8]);
                        acc[nt] = __builtin_amdgcn_mfma_f32_32x32x16_bf16(a, bb, acc[nt], 0, 0, 0);
                    }
                }
        }
        // rowsum: butterfly over 32 k-lanes; combine 4 k-slices via redR
        for (int reg = 0; reg < 16; ++reg) {
            float v = rsum[reg];
            v += __shfl_xor(v, 1, 64);
            v += __shfl_xor(v, 2, 64);
            v += __shfl_xor(v, 4, 64);
            v += __shfl_xor(v, 8, 64);
            v += __shfl_xor(v, 16, 64);
            int rr = (reg & 3) + 8 * (reg >> 2);
            if (l31 == 0) redR[wk4][wq2 * 32 + rr + 4 * lh] = v;
        }
        for (int nt = 0; nt < 2; ++nt) {
            int c = wcq * 64 + nt * 32 + l31;
            for (int reg = 0; reg < 16; ++reg) {
                int q = qt * 64 + wq2 * 32 + (reg & 3) + 8 * (reg >> 2) + 4 * lh;
                oab[((size_t)b * TT + q) * CC + c] = f2bf(acc[nt][reg]);
            }
        }
        __syncthreads();
        if (tid < 64)
            rowsum[(size_t)b * TT + qt * 64 + tid] =
                redR[0][tid] + redR[1][tid] + redR[2][tid] + redR[3][tid];
        __syncthreads();
    }
}

// ---------------------------------------------------------------------------
// conv: R24 — N-tile 64 -> 128 (output tile 128t x 128o). GEMM-ladder lever:
// MFMA per staged byte doubles (96 MFMA / 74KB-kc vs 48 / 45KB), A-tile
// re-reads halve (each A tile serves 128 outputs), barrier traversals per
// output halve. Grid 512 (+32 rowsm on conv1), 2 blocks/CU (LDS 74KB),
// launch_bounds(256,2) for the doubled acc (64 f32) + 12 B prefetch regs.
// R22 prefetch + R23 CSE/rowsm-absorption/fused-epilogue carried over
// (Ft re-sized to [128][131] fp32 = 67KB <= SL).
__global__ __launch_bounds__(256, 2)
void conv_kernel(const void* __restrict__ inp, int in_is_fp32,
                 const short* __restrict__ wbf, const float* __restrict__ bias,
                 void* __restrict__ outp, int out_is_bf16,
                 const float* __restrict__ xres, const float* __restrict__ wxv,
                 int fuse_final,
                 const float* __restrict__ rsin, float* __restrict__ wxout) {
    __shared__ short SL[130 * 72 + 6 * 64 * 72];   // As(130x72) | Bs(384x72); reused as Ft[128][131]
    short* As = SL;
    short* Bs = SL + 130 * 72;
    int tid = threadIdx.x, wv_ = tid >> 6, lane = tid & 63;
    int n15 = lane & 15, quad = lane >> 4;
    int bid = blockIdx.x;
    if (rsin != nullptr && bid >= 512) {           // rowsm side-task blocks
        float* red = (float*)SL;
        int b2 = bid - 512;
        float v[4];
        float m = -1e30f;
        for (int r2 = 0; r2 < 4; ++r2) {
            v[r2] = rsin[(size_t)b2 * TT + tid + 256 * r2];
            m = fmaxf(m, v[r2]);
        }
        red[tid] = m; __syncthreads();
        for (int s2 = 128; s2 > 0; s2 >>= 1) { if (tid < s2) red[tid] = fmaxf(red[tid], red[tid + s2]); __syncthreads(); }
        m = red[0]; __syncthreads();
        float e[4], zs = 0.f;
        for (int r2 = 0; r2 < 4; ++r2) { e[r2] = __expf(v[r2] - m); zs += e[r2]; }
        red[tid] = zs; __syncthreads();
        for (int s2 = 128; s2 > 0; s2 >>= 1) { if (tid < s2) red[tid] += red[tid + s2]; __syncthreads(); }
        float rz2 = 1.0f / red[0];
        for (int r2 = 0; r2 < 4; ++r2) wxout[(size_t)b2 * TT + tid + 256 * r2] = e[r2] * rz2;
        return;
    }
    int r = bid & 7;
    int n0 = ((bid >> 3) & 1) << 7;      // 0 or 128
    int bm = (bid >> 4) * 8 + r;         // 0..255
    int b = bm >> 3, mt = bm & 7;
    int t0 = mt * 128;
    f32x4 acc[2][8];
    for (int i = 0; i < 2; ++i) for (int j = 0; j < 8; ++j)
        for (int p = 0; p < 4; ++p) acc[i][j][p] = 0.f;

    s8 aregs[5], bregs[12];
    if (!in_is_fp32) {                 // preload kc=0 A tile into regs
        const short* in = (const short*)inp;
        for (int it = 0; it < 5; ++it) {
            int idx = tid + 256 * it;
            int row = idx >> 3, seg = idx & 7;
            if (row < 130) {
                int t = t0 + row - 2;
                s8 st;
                if (t >= 0) st = *reinterpret_cast<const s8*>(&in[((size_t)b * TT + t) * CC + seg * 8]);
                else for (int p = 0; p < 8; ++p) st[p] = 0;
                aregs[it] = st;
            }
        }
    }
    for (int it = 0; it < 12; ++it) {  // preload kc=0 B tile into regs (384 rows)
        int idx = tid + 256 * it;
        int row = idx >> 3, seg = idx & 7;
        int j = row >> 7, o = row & 127;
        bregs[it] = *reinterpret_cast<const s8*>(&wbf[((size_t)(j * 256 + n0 + o)) * 256 + seg * 8]);
    }

    for (int kc = 0; kc < 4; ++kc) {
        int c0 = kc * 64;
        __syncthreads();
        if (in_is_fp32) {
            const float* in = (const float*)inp;
            for (int it = 0; it < 9; ++it) {
                int idx = tid + 256 * it;
                int row = idx >> 4, fc = idx & 15;
                if (row < 130) {
                    int t = t0 + row - 2;
                    s4v st;
                    if (t >= 0) {
                        f4 v = *reinterpret_cast<const f4*>(&in[((size_t)b * TT + t) * CC + c0 + fc * 4]);
                        for (int p = 0; p < 4; ++p) st[p] = f2bf(v[p]);
                    } else { for (int p = 0; p < 4; ++p) st[p] = 0; }
                    *reinterpret_cast<s4v*>(&As[row * 72 + fc * 4]) = st;
                }
            }
        } else {
            for (int it = 0; it < 5; ++it) {
                int idx = tid + 256 * it;
                int row = idx >> 3, seg = idx & 7;
                if (row < 130)
                    *reinterpret_cast<s8*>(&As[row * 72 + seg * 8]) = aregs[it];
            }
        }
        for (int it = 0; it < 12; ++it) {
            int idx = tid + 256 * it;
            int row = idx >> 3, seg = idx & 7;
            *reinterpret_cast<s8*>(&Bs[row * 72 + seg * 8]) = bregs[it];
        }
        __syncthreads();
        if (kc < 3) {                  // prefetch kc+1 (hidden under MFMA below)
            int c0n = c0 + 64;
            if (!in_is_fp32) {
                const short* in = (const short*)inp;
                for (int it = 0; it < 5; ++it) {
                    int idx = tid + 256 * it;
                    int row = idx >> 3, seg = idx & 7;
                    if (row < 130) {
                        int t = t0 + row - 2;
                        s8 st;
                        if (t >= 0) st = *reinterpret_cast<const s8*>(&in[((size_t)b * TT + t) * CC + c0n + seg * 8]);
                        else for (int p = 0; p < 8; ++p) st[p] = 0;
                        aregs[it] = st;
                    }
                }
            }
            for (int it = 0; it < 12; ++it) {
                int idx = tid + 256 * it;
                int row = idx >> 3, seg = idx & 7;
                int j = row >> 7, o = row & 127;
                bregs[it] = *reinterpret_cast<const s8*>(&wbf[((size_t)(j * 256 + n0 + o)) * 256 + c0n + seg * 8]);
            }
        }
        for (int j = 0; j < 3; ++j)
            for (int ks = 0; ks < 2; ++ks) {
                s8 bfr[8];
                for (int nt = 0; nt < 8; ++nt)
                    bfr[nt] = *reinterpret_cast<const s8*>(&Bs[(j * 128 + nt * 16 + n15) * 72 + quad * 8 + ks * 32]);
                for (int mt2 = 0; mt2 < 2; ++mt2) {
                    s8 a = *reinterpret_cast<const s8*>(&As[(wv_ * 32 + mt2 * 16 + n15 + j) * 72 + quad * 8 + ks * 32]);
                    for (int nt = 0; nt < 8; ++nt)
                        acc[mt2][nt] = __builtin_amdgcn_mfma_f32_16x16x32_bf16(a, bfr[nt], acc[mt2][nt], 0, 0, 0);
                }
            }
    }
    if (!fuse_final) {
        for (int mt2 = 0; mt2 < 2; ++mt2)
            for (int nt = 0; nt < 8; ++nt) {
                int o = n0 + nt * 16 + n15;
                float bvl = bias[o];
                for (int reg = 0; reg < 4; ++reg) {
                    int t = t0 + wv_ * 32 + mt2 * 16 + quad * 4 + reg;
                    float v = fmaxf(acc[mt2][nt][reg] + bvl, 0.f);
                    if (out_is_bf16) ((short*)outp)[((size_t)b * TT + t) * CC + o] = f2bf(v);
                    else             ((float*)outp)[((size_t)b * TT + t) * CC + o] = v;
                }
            }
    } else {
        float* Ft = (float*)SL;            // [128][131] fp32 (67072 B <= SL)
        __syncthreads();                   // all LDS reads of As/Bs done
        for (int mt2 = 0; mt2 < 2; ++mt2)
            for (int nt = 0; nt < 8; ++nt) {
                int ol = nt * 16 + n15;
                float bvl = bias[n0 + ol];
                for (int reg = 0; reg < 4; ++reg) {
                    int tl = wv_ * 32 + mt2 * 16 + quad * 4 + reg;
                    Ft[tl * 131 + ol] = fmaxf(acc[mt2][nt][reg] + bvl, 0.f);
                }
            }
        __syncthreads();
        int c_l = tid >> 5;                // 0..7
        int t_l = (tid & 31) * 4;          // 0..124
        f4 wv4 = *reinterpret_cast<const f4*>(&wxv[(size_t)b * TT + t0 + t_l]);
        for (int pass = 0; pass < 16; ++pass) {
            int c = n0 + pass * 8 + c_l;
            f4 xv = *reinterpret_cast<const f4*>(&xres[((size_t)b * CC + c) * TT + t0 + t_l]);
            f4 rr;
            for (int p = 0; p < 4; ++p)
                rr[p] = fmaxf(Ft[(t_l + p) * 131 + pass * 8 + c_l] + xv[p] * (1.f + wv4[p]), 0.f);
            *reinterpret_cast<f4*>(&((float*)outp)[((size_t)b * CC + c) * TT + t0 + t_l]) = rr;
        }
    }
}

// ---------------------------------------------------------------------------
extern "C" void kernel_launch(void* const* d_in, const int* in_sizes, int n_in,
                              void* d_out, int out_size, void* d_ws, size_t ws_size,
                              hipStream_t stream) {
    (void)in_sizes; (void)n_in; (void)out_size; (void)ws_size;
    const float* x  = (const float*)d_in[0];
    const float* wq = (const float*)d_in[1];
    const float* bq = (const float*)d_in[2];
    const float* wk = (const float*)d_in[3];
    const float* bk = (const float*)d_in[4];
    const float* wv = (const float*)d_in[5];
    const float* bv = (const float*)d_in[6];
    const float* v1 = (const float*)d_in[7];
    const float* g1 = (const float*)d_in[8];
    const float* b1 = (const float*)d_in[9];
    const float* v2 = (const float*)d_in[10];
    const float* g2 = (const float*)d_in[11];
    const float* b2 = (const float*)d_in[12];
    char* ws = (char*)d_ws;
    float* out = (float*)d_out;

    short* qbf  = (short*)(ws + OFF_QBF);
    short* kbf  = (short*)(ws + OFF_KBF);
    short* vt   = (short*)(ws + OFF_VT);
    short* xt   = (short*)(ws + OFF_OA);   // xt bf16 (dead after qkv)
    short* oab  = (short*)(ws + OFF_OA);   // oa bf16 (attn out; dead after conv1)
    short* c1   = (short*)(ws + OFF_C1);
    float* crz  = (float*)(ws + OFF_CRZ);
    float* rs   = (float*)(ws + OFF_RS);
    float* wxb  = (float*)(ws + OFF_WX);
    short* w1bf = (short*)(ws + OFF_W1);
    short* w2bf = (short*)(ws + OFF_W2);
    short* wqkv = (short*)(ws + OFF_WQKV);

    wnpack_kernel<<<dim3(608), dim3(256), 0, stream>>>(v1, g1, v2, g2, wq, wk, wv,
                                                       w1bf, w2bf, wqkv);
    transpose_kernel<<<dim3(4, 16, 32), dim3(256), 0, stream>>>(x, xt);
    qkv_kernel<<<dim3(1536), dim3(256), 0, stream>>>(xt, wqkv, bq, bk, bv, qbf, kbf, vt);
    colz_kernel<<<dim3(256), dim3(512), 0, stream>>>(qbf, kbf, crz);
    attn_kernel<<<dim3(256), dim3(512), 0, stream>>>(qbf, kbf, vt, crz, oab, rs);
    conv_kernel<<<dim3(544), dim3(256), 0, stream>>>(oab, 0, w1bf, b1, c1, 1,
                                                     nullptr, nullptr, 0, rs, wxb);
    conv_kernel<<<dim3(512), dim3(256), 0, stream>>>(c1, 0, w2bf, b2, out, 0,
                                                     x, wxb, 1, nullptr, nullptr);
}